// Round 16
// baseline (2056.891 us; speedup 1.0000x reference)
//
#include <hip/hip_runtime.h>
#include <math.h>

#define TS    1024
#define DM    1024
#define BB    4
#define HH    8
#define LL    3
#define NLAT  24
#define NROWS 4096
#define DFF   4096

typedef _Float16 f16x8 __attribute__((ext_vector_type(8)));
typedef float f32x4 __attribute__((ext_vector_type(4)));
typedef unsigned short u16x4 __attribute__((ext_vector_type(4)));
typedef unsigned short u16x8 __attribute__((ext_vector_type(8)));

__device__ __forceinline__ unsigned short f16h(float x) {
  _Float16 h = (_Float16)x;
  return __builtin_bit_cast(unsigned short, h);
}
__device__ __forceinline__ float f16tof(unsigned short u) {
  _Float16 h = __builtin_bit_cast(_Float16, u);
  return (float)h;
}
__device__ __forceinline__ void gl16(const void* g, void* l) {
  __builtin_amdgcn_global_load_lds(
      (const __attribute__((address_space(1))) void*)g,
      (__attribute__((address_space(3))) void*)l, 16, 0, 0);
}

template <int N>
__device__ __forceinline__ void wait_vm() {
  static_assert(N == 0 || N == 2 || N == 3 || N == 4 || N == 5 || N == 6 ||
                N == 8 || N == 10 || N == 12 || N == 16, "vmcnt literal");
  if constexpr (N == 0) asm volatile("s_waitcnt vmcnt(0)" ::: "memory");
  else if constexpr (N == 2) asm volatile("s_waitcnt vmcnt(2)" ::: "memory");
  else if constexpr (N == 3) asm volatile("s_waitcnt vmcnt(3)" ::: "memory");
  else if constexpr (N == 4) asm volatile("s_waitcnt vmcnt(4)" ::: "memory");
  else if constexpr (N == 5) asm volatile("s_waitcnt vmcnt(5)" ::: "memory");
  else if constexpr (N == 6) asm volatile("s_waitcnt vmcnt(6)" ::: "memory");
  else if constexpr (N == 8) asm volatile("s_waitcnt vmcnt(8)" ::: "memory");
  else if constexpr (N == 10) asm volatile("s_waitcnt vmcnt(10)" ::: "memory");
  else if constexpr (N == 12) asm volatile("s_waitcnt vmcnt(12)" ::: "memory");
  else asm volatile("s_waitcnt vmcnt(16)" ::: "memory");
}

// ---------------- reductions ----------------
__device__ __forceinline__ float waveAllSum(float v) {
#pragma unroll
  for (int m = 32; m >= 1; m >>= 1) v += __shfl_xor(v, m);
  return v;
}
__device__ __forceinline__ float waveAllMax(float v) {
#pragma unroll
  for (int m = 32; m >= 1; m >>= 1) v = fmaxf(v, __shfl_xor(v, m));
  return v;
}
__device__ __forceinline__ float blockSum(float v, float* red, int nw) {
  v = waveAllSum(v);
  int lane = threadIdx.x & 63, wid = threadIdx.x >> 6;
  __syncthreads();
  if (lane == 0) red[wid] = v;
  __syncthreads();
  float t = 0.f;
  for (int i = 0; i < nw; i++) t += red[i];
  return t;
}
__device__ __forceinline__ float blockMax(float v, float* red, int nw) {
  v = waveAllMax(v);
  int lane = threadIdx.x & 63, wid = threadIdx.x >> 6;
  __syncthreads();
  if (lane == 0) red[wid] = v;
  __syncthreads();
  float t = -INFINITY;
  for (int i = 0; i < nw; i++) t = fmaxf(t, red[i]);
  return t;
}

// ---------------- tables ----------------
__global__ __launch_bounds__(256) void build_C_pp(unsigned short* __restrict__ ch,
                                                  unsigned short* __restrict__ cl) {
  int i = blockIdx.x * 256 + threadIdx.x;
  int t = i >> 10, s = i & 1023;
  int m = (t * s) & 1023;
  float ang = (float)m * 6.135923151542565e-3f;
  float c = cosf(ang);
  unsigned short h = f16h(c);
  ch[i] = h;
  cl[i] = f16h(c - f16tof(h));
}

__global__ void build_filt(float* __restrict__ filt,
                           const float* __restrict__ alpha,
                           const float* __restrict__ fscale) {
  int t = threadIdx.x;
  float fr = (t < 512) ? (float)t : (float)(t - 1024);
  fr *= (1.0f / 1024.0f);
  float km = fmaxf(fabsf(fr), 1e-10f);
  float la = atanf(logf(km));
  for (int l = 0; l < LL; l++) {
    float aa = alpha[l] + fscale[l] * (1.5f - 1.5f);
    filt[l * TS + t] = expf(-aa * la);
  }
}

__global__ void biascat3(const float* __restrict__ qb, const float* __restrict__ kb,
                         const float* __restrict__ vb, float* __restrict__ out) {
  int i = blockIdx.x * 256 + threadIdx.x;  // 0..3071
  const float* s = (i < 1024) ? qb : ((i < 2048) ? kb : vb);
  out[i] = s[i & 1023];
}

// transpose W_el [1024][24] -> W_elT [24][1024]
__global__ __launch_bounds__(256) void trans_wel(const float* __restrict__ W_el,
                                                 float* __restrict__ W_elT) {
  int i = blockIdx.x * 256 + threadIdx.x;   // 0 .. 24*1024-1
  int j = i >> 10, d = i & 1023;
  W_elT[i] = W_el[(size_t)d * NLAT + j];
}

// ---------------- embedding ----------------
__global__ __launch_bounds__(256) void embed_kernel(
    const int* __restrict__ ids, const float* __restrict__ tok_table,
    const float* __restrict__ emb_scales, const float* __restrict__ emb_norm,
    const float* __restrict__ pos_emb, float* __restrict__ x) {
  __shared__ float red[4];
  int row = blockIdx.x;
  int t = row & (TS - 1);
  int tid = threadIdx.x;
  const float* tok = tok_table + (size_t)ids[row] * DM;
  float ev[4];
  float st = 0.f, se = 0.f;
#pragma unroll
  for (int kk = 0; kk < 4; kk++) {
    int d = tid + kk * 256;
    float tv = tok[d];
    float e = tv * emb_scales[d];
    ev[kk] = e;
    st += tv * tv;
    se += e * e;
  }
  st = blockSum(st, red, 4);
  se = blockSum(se, red, 4);
  float sc = sqrtf(st) / (sqrtf(se) + 1e-8f) * emb_norm[0];
  float* xr = x + (size_t)row * DM;
  const float* pr = pos_emb + (size_t)t * DM;
#pragma unroll
  for (int kk = 0; kk < 4; kk++) {
    int d = tid + kk * 256;
    xr[d] = ev[kk] * sc + pr[d];
  }
}

// ---------------- Leech lattice: 1 wave/row, no LDS, no barriers ----------------
__global__ __launch_bounds__(256) void leech_wave(
    float* __restrict__ x, const float* __restrict__ W_elT,
    const float* __restrict__ b_el, const float* __restrict__ W_le,
    const float* __restrict__ b_le, const float* __restrict__ ecs_p,
    const float* __restrict__ epres_p) {
  int tid = threadIdx.x;
  int wv = tid >> 6, lane = tid & 63;
  int row = blockIdx.x * 4 + wv;
  float ecs = ecs_p[0], epres = epres_p[0];
  float* xr = x + (size_t)row * DM;

  float acc[NLAT];
#pragma unroll
  for (int j = 0; j < NLAT; j++) acc[j] = 0.f;
  float sx = 0.f;
  for (int kk = 0; kk < 16; kk++) {
    int d = lane + 64 * kk;
    float v = xr[d];
    sx += v * v;
#pragma unroll
    for (int j = 0; j < NLAT; j++) acc[j] = fmaf(v, W_elT[j * DM + d], acc[j]);
  }
  sx = waveAllSum(sx);
  float ie = sqrtf(sx);
#pragma unroll
  for (int j = 0; j < NLAT; j++) acc[j] = waveAllSum(acc[j]);

  float corr[NLAT];
  float slp = 0.f;
#pragma unroll
  for (int j = 0; j < NLAT; j++) {
    float l = rintf((acc[j] + b_el[j]) / ecs) * ecs;
    acc[j] = l;
    slp = fmaf(l, l, slp);
  }
  float nlp = sqrtf(slp);
  float s1 = ie / (nlp + 1e-8f) * epres;
  float ie2 = fabsf(s1) * nlp;
#pragma unroll
  for (int j = 0; j < NLAT; j++) {
    float e = acc[j] * s1;
    corr[j] = (fabsf(e) > ecs) ? e : 0.f;
  }

  float sd = 0.f;
  for (int kk = 0; kk < 16; kk++) {
    int d = lane + 64 * kk;
    float v = b_le[d];
#pragma unroll
    for (int j = 0; j < NLAT; j++) v = fmaf(corr[j], W_le[j * DM + d], v);
    sd = fmaf(v, v, sd);
  }
  sd = waveAllSum(sd);
  float sc2 = ie2 / (sqrtf(sd) + 1e-8f) * epres;

  for (int kk = 0; kk < 16; kk++) {
    int d = lane + 64 * kk;
    float v = b_le[d];
#pragma unroll
    for (int j = 0; j < NLAT; j++) v = fmaf(corr[j], W_le[j * DM + d], v);
    xr[d] = fmaf(v, sc2, xr[d]);
  }
}

// ---------------- LayerNorm -> f16 hi (+optional lo) planes ----------------
__global__ __launch_bounds__(256) void ln_pp(
    const float* __restrict__ x, const float* __restrict__ w,
    const float* __restrict__ b, unsigned short* __restrict__ oHi,
    unsigned short* __restrict__ oLo, float* __restrict__ hnorm) {
  __shared__ float red[4];
  int row = blockIdx.x, tid = threadIdx.x;
  const float4 v = ((const float4*)(x + (size_t)row * DM))[tid];
  float s = v.x + v.y + v.z + v.w;
  s = blockSum(s, red, 4);
  float mean = s * (1.f / 1024.f);
  float dx = v.x - mean, dy = v.y - mean, dz = v.z - mean, dw = v.w - mean;
  float ss = dx * dx + dy * dy + dz * dz + dw * dw;
  ss = blockSum(ss, red, 4);
  float inv = 1.f / sqrtf(ss * (1.f / 1024.f) + 1e-5f);
  const float4 wv = ((const float4*)w)[tid];
  const float4 bv = ((const float4*)b)[tid];
  float hv[4];
  hv[0] = dx * inv * wv.x + bv.x;
  hv[1] = dy * inv * wv.y + bv.y;
  hv[2] = dz * inv * wv.z + bv.z;
  hv[3] = dw * inv * wv.w + bv.w;
  u16x4 hh;
#pragma unroll
  for (int j = 0; j < 4; j++) hh[j] = f16h(hv[j]);
  *(u16x4*)(oHi + (size_t)row * DM + tid * 4) = hh;
  if (oLo) {
    u16x4 ll;
#pragma unroll
    for (int j = 0; j < 4; j++) ll[j] = f16h(hv[j] - f16tof(hh[j]));
    *(u16x4*)(oLo + (size_t)row * DM + tid * 4) = ll;
  }
  if (hnorm) {
    float hs = hv[0]*hv[0] + hv[1]*hv[1] + hv[2]*hv[2] + hv[3]*hv[3];
    hs = blockSum(hs, red, 4);
    if (tid == 0) hnorm[row] = sqrtf(hs);
  }
}

// ---------------- fp32 -> transposed f16 hi (+optional lo) planes ----------------
__global__ __launch_bounds__(256) void tsplit_f32(
    const float* __restrict__ in, unsigned short* __restrict__ oHi,
    unsigned short* __restrict__ oLo, int ldin, int ldout, float scale) {
  __shared__ float T[64][65];
  int r0 = blockIdx.y * 64, c0 = blockIdx.x * 64;
  int tid = threadIdx.x;
  int r = tid >> 2, s = tid & 3;
  const float* ip = in + (size_t)(r0 + r) * ldin + c0 + s * 16;
#pragma unroll
  for (int q = 0; q < 4; q++) {
    float4 v = ((const float4*)ip)[q];
    T[r][s * 16 + q * 4 + 0] = v.x;
    T[r][s * 16 + q * 4 + 1] = v.y;
    T[r][s * 16 + q * 4 + 2] = v.z;
    T[r][s * 16 + q * 4 + 3] = v.w;
  }
  __syncthreads();
  u16x8 h0, h1, l0, l1;
#pragma unroll
  for (int q = 0; q < 16; q++) {
    float v = T[s * 16 + q][r] * scale;
    unsigned short h = f16h(v);
    if (q < 8) h0[q] = h; else h1[q - 8] = h;
    if (oLo) {
      unsigned short l = f16h(v - f16tof(h));
      if (q < 8) l0[q] = l; else l1[q - 8] = l;
    }
  }
  size_t ob = (size_t)(c0 + r) * ldout + r0 + s * 16;
  *(u16x8*)(oHi + ob) = h0;
  *(u16x8*)(oHi + ob + 8) = h1;
  if (oLo) {
    *(u16x8*)(oLo + ob) = l0;
    *(u16x8*)(oLo + ob + 8) = l1;
  }
}

// ---------------- u16 plane transpose (batched) ----------------
__global__ __launch_bounds__(256) void tsplit_u16(
    const unsigned short* __restrict__ in, unsigned short* __restrict__ out,
    int ldin, int ldout, long sIn, long sOut) {
  __shared__ unsigned short T[64][68];
  int z = blockIdx.z;
  in += (size_t)z * sIn;
  out += (size_t)z * sOut;
  int r0 = blockIdx.y * 64, c0 = blockIdx.x * 64;
  int tid = threadIdx.x;
  int r = tid >> 2, s = tid & 3;
  const unsigned short* ip = in + (size_t)(r0 + r) * ldin + c0 + s * 16;
  u16x8 a = *(const u16x8*)ip;
  u16x8 b = *(const u16x8*)(ip + 8);
#pragma unroll
  for (int q = 0; q < 8; q++) {
    T[r][s * 16 + q] = a[q];
    T[r][s * 16 + 8 + q] = b[q];
  }
  __syncthreads();
  u16x8 o0, o1;
#pragma unroll
  for (int q = 0; q < 8; q++) {
    o0[q] = T[s * 16 + q][r];
    o1[q] = T[s * 16 + 8 + q][r];
  }
  size_t ob = (size_t)(c0 + r) * ldout + r0 + s * 16;
  *(u16x8*)(out + ob) = o0;
  *(u16x8*)(out + ob + 8) = o1;
}

// ---------------- split-f16 MFMA GEMM, TMIx128 tile, BK=NKC*8 ----------------
enum { E_PP = 0, E_QKV, E_F32, E_F32_BIAS, E_P1_GELU, E_F32_ACC_BIAS, E_F32_ATOMIC, E_V, E_P16 };

template <int EPI, bool ALO, bool BLO, int TMI, int DEPTH, int NKC = 4>
__global__ __launch_bounds__(256, 2) void gemmT(
    const unsigned short* __restrict__ Ah, const unsigned short* __restrict__ Al,
    const unsigned short* __restrict__ Bh, const unsigned short* __restrict__ Bl,
    void* __restrict__ C, void* __restrict__ C2, void* __restrict__ C3,
    void* __restrict__ C4, void* __restrict__ C5,
    const float* __restrict__ bias, const float* __restrict__ filtp, float desc,
    int K, int lda, int ldb, int ldc, int zdiv,
    long sAa, long sAb, long sBa, long sBb, long sCa, long sCb) {
  constexpr int NMA = 1 + (ALO ? 1 : 0);
  constexpr int NMB = 1 + (BLO ? 1 : 0);
  constexpr int HA = TMI / 64;
  constexpr int CA = NMA * NKC * HA;
  constexpr int CB = NMB * NKC * 2;
  constexpr int CPW = (CA + CB) / 4;
  constexpr int MI = TMI / 32;
  constexpr int BK = NKC * 8;
  constexpr int NBUF = DEPTH + 1;
  __shared__ __align__(16) unsigned short smA[NBUF][NMA][NKC][TMI][8];
  __shared__ __align__(16) unsigned short smB[NBUF][NMB][NKC][128][8];

  const int gx = gridDim.x, gy = gridDim.y;
  const int nb = gx * gy * gridDim.z;
  const int lid = (blockIdx.z * gy + blockIdx.y) * gx + blockIdx.x;
  const int cpx = nb >> 3;
  const int swz = (lid & 7) * cpx + (lid >> 3);
  const int bxi = swz % gx;
  const int tmp2 = swz / gx;
  const int byi = tmp2 % gy;
  const int bzi = tmp2 / gy;

  const int w = threadIdx.x >> 6, lane = threadIdx.x & 63;
  const int wm = w >> 1, wn = w & 1;
  const int bm = byi * TMI, bn = bxi * 128;
  const int za = bzi / zdiv, zb = bzi % zdiv;
  const long Ao = (long)za * sAa + (long)zb * sAb;
  const long Bo = (long)za * sBa + (long)zb * sBb;

  f32x4 acc[MI][4];
#pragma unroll
  for (int i = 0; i < MI; i++)
#pragma unroll
    for (int j = 0; j < 4; j++) acc[i][j] = (f32x4){0.f, 0.f, 0.f, 0.f};

  auto stage = [&](int buf, int k0) {
#pragma unroll
    for (int c = 0; c < CPW; c++) {
      int id = w + 4 * c;
      if (id < CA) {
        int pl = id / (NKC * HA);
        int rem = id - pl * NKC * HA;
        int kc = rem / HA, half = rem - kc * HA;
        const unsigned short* src =
            (pl ? Al : Ah) + Ao + (size_t)(bm + half * 64 + lane) * lda + k0 + kc * 8;
        gl16(src, (void*)&smA[buf][pl][kc][half * 64][0]);
      } else {
        int bid = id - CA;
        int pl = bid / (NKC * 2);
        int rem = bid - pl * NKC * 2;
        int kc = rem >> 1, half = rem & 1;
        const unsigned short* src =
            (pl ? Bl : Bh) + Bo + (size_t)(bn + half * 64 + lane) * ldb + k0 + kc * 8;
        gl16(src, (void*)&smB[buf][pl][kc][half * 64][0]);
      }
    }
  };

  const int nt = K / BK;
  stage(0, 0);
  if (DEPTH == 2 && nt > 1) stage(1, BK);
  int cur = 0, nxt = (DEPTH == 2) ? 2 : 1;
  for (int t = 0; t < nt; t++) {
    if constexpr (DEPTH == 1) {
      if (t + 1 < nt) {
        stage(nxt, (t + 1) * BK);
        wait_vm<CPW>();
      } else {
        wait_vm<0>();
      }
    } else {
      if (t + 2 < nt) {
        stage(nxt, (t + 2) * BK);
        wait_vm<2 * CPW>();
      } else if (t + 1 < nt) {
        wait_vm<CPW>();
      } else {
        wait_vm<0>();
      }
    }
    __builtin_amdgcn_s_barrier();
    __builtin_amdgcn_sched_barrier(0);

    const int fr = lane & 15, kc2 = lane >> 4;
#pragma unroll
    for (int kb = 0; kb < NKC / 4; kb++) {
      const int kcc = 4 * kb + kc2;
      f16x8 ah[MI], bh[4], alx[MI], blx[4];
#pragma unroll
      for (int i = 0; i < MI; i++) {
        ah[i] = *(const f16x8*)&smA[cur][0][kcc][wm * (TMI / 2) + i * 16 + fr][0];
        if (ALO) alx[i] = *(const f16x8*)&smA[cur][NMA - 1][kcc][wm * (TMI / 2) + i * 16 + fr][0];
      }
#pragma unroll
      for (int j = 0; j < 4; j++) {
        bh[j] = *(const f16x8*)&smB[cur][0][kcc][wn * 64 + j * 16 + fr][0];
        if (BLO) blx[j] = *(const f16x8*)&smB[cur][NMB - 1][kcc][wn * 64 + j * 16 + fr][0];
      }
#pragma unroll
      for (int i = 0; i < MI; i++)
#pragma unroll
        for (int j = 0; j < 4; j++) {
          acc[i][j] = __builtin_amdgcn_mfma_f32_16x16x32_f16(ah[i], bh[j], acc[i][j], 0, 0, 0);
          if (BLO) acc[i][j] = __builtin_amdgcn_mfma_f32_16x16x32_f16(ah[i], blx[j], acc[i][j], 0, 0, 0);
          if (ALO) acc[i][j] = __builtin_amdgcn_mfma_f32_16x16x32_f16(alx[i], bh[j], acc[i][j], 0, 0, 0);
        }
    }
    __builtin_amdgcn_sched_barrier(0);
    __builtin_amdgcn_s_barrier();
    cur = (cur == NBUF - 1) ? 0 : cur + 1;
    nxt = (nxt == NBUF - 1) ? 0 : nxt + 1;
  }

  const int fr0 = lane & 15, rg = lane >> 4;
  const int colb = bn + wn * 64 + fr0;
  const int rowb = bm + wm * (TMI / 2) + rg * 4;
  const long Co = (long)za * sCa + (long)zb * sCb;
#pragma unroll
  for (int i = 0; i < MI; i++)
#pragma unroll
    for (int j = 0; j < 4; j++)
#pragma unroll
      for (int r = 0; r < 4; r++) {
        int row = rowb + i * 16 + r;
        int col = colb + j * 16;
        float v = acc[i][j][r] * desc;
        long idx = Co + (long)row * ldc + col;
        if constexpr (EPI == E_PP) {
          unsigned short h = f16h(v);
          ((unsigned short*)C)[idx] = h;
          ((unsigned short*)C2)[idx] = f16h(v - f16tof(h));
        } else if constexpr (EPI == E_QKV) {
          int t2 = row & (TS - 1);
          v *= filtp[t2];
          if (t2 == 0) v = fmaf(1024.f * filtp[0], bias[col], v);
          int seg = col >> 10, nn = col & 1023;
          long oix = (long)row * 1024 + nn;
          if (seg == 0) {
            unsigned short h = f16h(v);
            ((unsigned short*)C)[oix] = h;
            ((unsigned short*)C2)[oix] = f16h(v - f16tof(h));
          } else {
            unsigned short h = f16h(v);
            ((unsigned short*)C3)[oix] = h;
            ((unsigned short*)C4)[oix] = f16h(v - f16tof(h));
          }
        } else if constexpr (EPI == E_V) {
          int t2 = row & (TS - 1);
          v *= filtp[t2];
          if (t2 == 0) v = fmaf(1024.f * filtp[0], bias[col], v);
          ((unsigned short*)C)[idx] = f16h(v);
        } else if constexpr (EPI == E_P16) {
          ((unsigned short*)C)[idx] = f16h(v);
        } else if constexpr (EPI == E_F32) {
          ((float*)C)[idx] = v;
        } else if constexpr (EPI == E_F32_BIAS) {
          ((float*)C)[idx] = v + bias[col];
        } else if constexpr (EPI == E_P1_GELU) {
          v += bias[col];
          v = 0.5f * v * (1.f + erff(v * 0.7071067811865476f));
          ((unsigned short*)C)[idx] = f16h(v);
        } else if constexpr (EPI == E_F32_ACC_BIAS) {
          ((float*)C)[idx] += v + bias[col];
        } else {  // E_F32_ATOMIC
          if (za == 0) v += bias[col];
          atomicAdd(&((float*)C)[(long)row * ldc + col], v);
        }
      }
}

// ---------------- softmax -> f16 plane ----------------
__global__ __launch_bounds__(256) void softmax_p(const float* __restrict__ S,
                                                 unsigned short* __restrict__ P,
                                                 float scale) {
  __shared__ float red[4];
  int row = blockIdx.x, tid = threadIdx.x;
  float4 v = ((const float4*)(S + (size_t)row * 1024))[tid];
  v.x *= scale; v.y *= scale; v.z *= scale; v.w *= scale;
  float m = fmaxf(fmaxf(v.x, v.y), fmaxf(v.z, v.w));
  m = blockMax(m, red, 4);
  float4 e;
  e.x = expf(v.x - m); e.y = expf(v.y - m); e.z = expf(v.z - m); e.w = expf(v.w - m);
  float s = e.x + e.y + e.z + e.w;
  s = blockSum(s, red, 4);
  float inv = 1.f / s;
  u16x4 o;
  o[0] = f16h(e.x * inv); o[1] = f16h(e.y * inv);
  o[2] = f16h(e.z * inv); o[3] = f16h(e.w * inv);
  *(u16x4*)(P + (size_t)row * 1024 + tid * 4) = o;
}

// ---------------- out-scale + residual ----------------
__global__ __launch_bounds__(256) void outscale_kernel(
    float* __restrict__ x, const float* __restrict__ outp,
    const float* __restrict__ hnorm, const float* __restrict__ enorm_l) {
  __shared__ float red[4];
  int row = blockIdx.x, tid = threadIdx.x;
  float4 v = ((const float4*)(outp + (size_t)row * DM))[tid];
  float ss = v.x * v.x + v.y * v.y + v.z * v.z + v.w * v.w;
  ss = blockSum(ss, red, 4);
  float sc = hnorm[row] / (sqrtf(ss) + 1e-8f) * enorm_l[0];
  float4* xp = (float4*)(x + (size_t)row * DM);
  float4 xv = xp[tid];
  xv.x = fmaf(v.x, sc, xv.x);
  xv.y = fmaf(v.y, sc, xv.y);
  xv.z = fmaf(v.z, sc, xv.z);
  xv.w = fmaf(v.w, sc, xv.w);
  xp[tid] = xv;
}

// ---------------- two-stage mean-pool + classifier ----------------
__global__ __launch_bounds__(256) void pool_partial(const float* __restrict__ x,
                                                    float* __restrict__ part) {
  int b = blockIdx.x, c = blockIdx.y, tid = threadIdx.x;
  const float* xb = x + ((size_t)b * TS + c * 64) * DM;
  float4 s = {0.f, 0.f, 0.f, 0.f};
  for (int r = 0; r < 64; r++) {
    float4 v = ((const float4*)(xb + (size_t)r * DM))[tid];
    s.x += v.x; s.y += v.y; s.z += v.z; s.w += v.w;
  }
  ((float4*)(part + (size_t)(b * 16 + c) * DM))[tid] = s;
}
__global__ __launch_bounds__(1024) void pool_cls2(const float* __restrict__ part,
                                                  const float* __restrict__ clsW,
                                                  const float* __restrict__ clsb,
                                                  float* __restrict__ out) {
  __shared__ float red[16];
  int b = blockIdx.x, d = threadIdx.x;
  float s = 0.f;
  for (int c = 0; c < 16; c++) s += part[(size_t)(b * 16 + c) * DM + d];
  float p = s * (1.f / 1024.f);
  float a0 = p * clsW[d * 2 + 0];
  float a1 = p * clsW[d * 2 + 1];
  a0 = blockSum(a0, red, 16);
  a1 = blockSum(a1, red, 16);
  if (d == 0) {
    out[b * 2 + 0] = a0 + clsb[0];
    out[b * 2 + 1] = a1 + clsb[1];
  }
}

// ---------------- driver ----------------
extern "C" void kernel_launch(void* const* d_in, const int* in_sizes, int n_in,
                              void* d_out, int out_size, void* d_ws, size_t ws_size,
                              hipStream_t stream) {
  (void)in_sizes; (void)n_in; (void)out_size; (void)ws_size;
  const int*   ids        = (const int*)  d_in[0];
  const float* tok_table  = (const float*)d_in[1];
  const float* emb_scales = (const float*)d_in[2];
  const float* emb_norm   = (const float*)d_in[3];
  const float* pos_emb    = (const float*)d_in[4];
  const float* W_el       = (const float*)d_in[5];
  const float* b_el       = (const float*)d_in[6];
  const float* W_le       = (const float*)d_in[7];
  const float* b_le       = (const float*)d_in[8];
  const float* ecs        = (const float*)d_in[9];
  const float* epres      = (const float*)d_in[10];
  const float* ln1_w      = (const float*)d_in[11];
  const float* ln1_b      = (const float*)d_in[12];
  const float* ln2_w      = (const float*)d_in[13];
  const float* ln2_b      = (const float*)d_in[14];
  const float* qW = (const float*)d_in[15]; const float* qb = (const float*)d_in[16];
  const float* kW = (const float*)d_in[17]; const float* kb = (const float*)d_in[18];
  const float* vW = (const float*)d_in[19]; const float* vb = (const float*)d_in[20];
  const float* oW = (const float*)d_in[21]; const float* ob = (const float*)d_in[22];
  const float* f1W = (const float*)d_in[23]; const float* f1b = (const float*)d_in[24];
  const float* f2W = (const float*)d_in[25]; const float* f2b = (const float*)d_in[26];
  const float* alpha  = (const float*)d_in[27];
  const float* fscale = (const float*)d_in[28];
  const float* enorm  = (const float*)d_in[29];
  const float* clsW   = (const float*)d_in[30];
  const float* clsb   = (const float*)d_in[31];

  const size_t MB = 1u << 20;
  const long M1 = 1048576;
  char* p = (char*)d_ws;
  auto take = [&](size_t n) { char* r = p; p += n; return r; };
  unsigned short* CtH = (unsigned short*)take(2 * MB);
  unsigned short* CtL = (unsigned short*)take(2 * MB);
  float* filt    = (float*)take(16 * 1024);
  float* hnorm   = (float*)take(16 * 1024);
  float* bias3   = (float*)take(16 * 1024);
  float* W_elT   = (float*)take(128 * 1024);
  float* part    = (float*)take(1 * MB);
  float* x       = (float*)take(16 * MB);
  unsigned short* BIG = (unsigned short*)take(64 * MB);
  unsigned short* Hh  = BIG,            *Hl  = BIG + 4 * M1;
  unsigned short* HTh = BIG + 8 * M1,   *HTl = BIG + 12 * M1;
  unsigned short* HCh = BIG + 16 * M1,  *HCl = BIG + 20 * M1;
  unsigned short* WTh = BIG + 24 * M1,  *WTl = BIG + 28 * M1;
  unsigned short* P   = BIG;
  unsigned short* QFh = (unsigned short*)take(8 * MB);
  unsigned short* QFl = (unsigned short*)take(8 * MB);
  unsigned short* KFh = (unsigned short*)take(8 * MB);
  unsigned short* KFl = (unsigned short*)take(8 * MB);
  unsigned short* VT  = (unsigned short*)take(8 * MB);
  float* SREG = (float*)take(32 * MB);
  unsigned short* atth = (unsigned short*)SREG;
  float* OUTP = SREG + 4 * M1;
  unsigned short* MID = (unsigned short*)SREG;
  unsigned short* Vtmp = HTh;

  const float WS = 1024.f;
  const float DS = 1.f / 1024.f;
  const float scale = 0.08838834764831845f;

  build_C_pp<<<4096, 256, 0, stream>>>(CtH, CtL);
  build_filt<<<1, 1024, 0, stream>>>(filt, alpha, fscale);
  trans_wel<<<96, 256, 0, stream>>>(W_el, W_elT);
  embed_kernel<<<NROWS, 256, 0, stream>>>(ids, tok_table, emb_scales, emb_norm, pos_emb, x);
  leech_wave<<<1024, 256, 0, stream>>>(x, W_elT, b_el, W_le, b_le, ecs, epres);

  dim3 t44(16, 16, 4), t11(16, 16, 1);
  for (int i = 0; i < LL; i++) {
    ln_pp<<<NROWS, 256, 0, stream>>>(x, ln1_w + i * DM, ln1_b + i * DM, Hh, Hl, hnorm);
    tsplit_u16<<<dim3(16, 16, 8), 256, 0, stream>>>(Hh, HTh, 1024, 1024, M1, M1);
    gemmT<E_PP, true, true, 64, 2><<<dim3(8, 16, 4), 256, 0, stream>>>(
        CtH, CtL, HTh, HTl, HCh, HCl, nullptr, nullptr, nullptr,
        nullptr, nullptr, 1.f, 1024, 1024, 1024, 1024, 1, 0, 0, M1, 0, M1, 0);
    tsplit_f32<<<t11, 256, 0, stream>>>(qW + (size_t)i * M1, WTh, WTl, 1024, 1024, WS);
    tsplit_f32<<<t11, 256, 0, stream>>>(kW + (size_t)i * M1, WTh + M1, WTl + M1, 1024, 1024, WS);
    tsplit_f32<<<t11, 256, 0, stream>>>(vW + (size_t)i * M1, WTh + 2 * M1, nullptr, 1024, 1024, WS);
    biascat3<<<12, 256, 0, stream>>>(qb + i * DM, kb + i * DM, vb + i * DM, bias3);
    gemmT<E_QKV, true, true, 128, 1><<<dim3(16, 32, 1), 256, 0, stream>>>(
        HCh, HCl, WTh, WTl, QFh, QFl, KFh, KFl, nullptr,
        bias3, filt + i * TS, DS, 1024, 1024, 1024, 1024, 1, 0, 0, 0, 0, 0, 0);
    gemmT<E_V, false, false, 64, 2><<<dim3(8, 64, 1), 256, 0, stream>>>(
        HCh, nullptr, WTh + 2 * M1, nullptr, Vtmp, nullptr, nullptr, nullptr, nullptr,
        vb + i * DM, filt + i * TS, DS, 1024, 1024, 1024, 1024, 1, 0, 0, 0, 0, 0, 0);
    tsplit_u16<<<t44, 256, 0, stream>>>(Vtmp, VT, 1024, 1024, M1, M1);
    // attention: QKT at TMI=64 (1024 blocks) per b; softmax; batched PV (f16-only)
    for (int b = 0; b < BB; b++) {
      gemmT<E_F32, true, true, 64, 1><<<dim3(8, 16, 8), 256, 0, stream>>>(
          QFh + (size_t)b * M1, QFl + (size_t)b * M1,
          KFh + (size_t)b * M1, KFl + (size_t)b * M1,
          SREG, nullptr, nullptr, nullptr, nullptr,
          nullptr, nullptr, 1.f, 128, 1024, 1024, 1024, 1, 128, 0, 128, 0, M1, 0);
      softmax_p<<<HH * TS, 256, 0, stream>>>(SREG, P + (size_t)b * 8 * M1, scale);
    }
    gemmT<E_P16, false, false, 64, 2><<<dim3(1, 16, 32), 256, 0, stream>>>(
        P, nullptr, VT, nullptr, atth, nullptr, nullptr, nullptr, nullptr,
        nullptr, nullptr, 1.f, 1024, 1024, 1024, 1024, 8,
        8L * M1, M1, M1, 131072, M1, 128);
    // o-proj: 1-term, TMI=64, no split-K -> direct f32+bias store (no memset/atomics)
    tsplit_f32<<<t11, 256, 0, stream>>>(oW + (size_t)i * M1, WTh, nullptr, 1024, 1024, WS);
    gemmT<E_F32_BIAS, false, false, 64, 2><<<dim3(8, 64, 1), 256, 0, stream>>>(
        atth, nullptr, WTh, nullptr, OUTP, nullptr, nullptr, nullptr, nullptr,
        ob + i * DM, nullptr, DS, 1024, 1024, 1024, 1024, 1, 0, 0, 0, 0, 0, 0);
    outscale_kernel<<<NROWS, 256, 0, stream>>>(x, OUTP, hnorm, enorm + i);
    // FFN
    ln_pp<<<NROWS, 256, 0, stream>>>(x, ln2_w + i * DM, ln2_b + i * DM, Hh, nullptr, nullptr);
    tsplit_f32<<<dim3(64, 16, 1), 256, 0, stream>>>(f1W + (size_t)i * 4 * M1, WTh, nullptr, 4096, 1024, WS);
    // FFN1: 1-term, TMI=64, grid (32,64)=2048 -> ~6 blocks/CU
    gemmT<E_P1_GELU, false, false, 64, 1><<<dim3(32, 64, 1), 256, 0, stream>>>(
        Hh, nullptr, WTh, nullptr, MID, nullptr, nullptr, nullptr, nullptr,
        f1b + i * DFF, nullptr, DS, 1024, 1024, 1024, 4096, 1, 0, 0, 0, 0, 0, 0);
    tsplit_f32<<<dim3(16, 64, 1), 256, 0, stream>>>(f2W + (size_t)i * 4 * M1, WTh, nullptr, 1024, 4096, WS);
    // FFN2: 1-term, TMI=64, split-K=4, grid (8,64,4)=2048; atomic += into x
    gemmT<E_F32_ATOMIC, false, false, 64, 1><<<dim3(8, 64, 4), 256, 0, stream>>>(
        MID, nullptr, WTh, nullptr, x, nullptr, nullptr, nullptr, nullptr,
        f2b + i * DM, nullptr, DS, 1024, 4096, 4096, 1024, 1, 1024, 0, 1024, 0, 0, 0);
  }
  pool_partial<<<dim3(BB, 16), 256, 0, stream>>>(x, part);
  pool_cls2<<<BB, 1024, 0, stream>>>(part, clsW, clsb, (float*)d_out);
}

// Round 17
// 1819.378 us; speedup vs baseline: 1.1305x; 1.1305x over previous
//
#include <hip/hip_runtime.h>
#include <math.h>

#define TS    1024
#define DM    1024
#define BB    4
#define HH    8
#define LL    3
#define NLAT  24
#define NROWS 4096
#define DFF   4096

typedef _Float16 f16x8 __attribute__((ext_vector_type(8)));
typedef float f32x4 __attribute__((ext_vector_type(4)));
typedef unsigned short u16x4 __attribute__((ext_vector_type(4)));
typedef unsigned short u16x8 __attribute__((ext_vector_type(8)));

__device__ __forceinline__ unsigned short f16h(float x) {
  _Float16 h = (_Float16)x;
  return __builtin_bit_cast(unsigned short, h);
}
__device__ __forceinline__ float f16tof(unsigned short u) {
  _Float16 h = __builtin_bit_cast(_Float16, u);
  return (float)h;
}
__device__ __forceinline__ void gl16(const void* g, void* l) {
  __builtin_amdgcn_global_load_lds(
      (const __attribute__((address_space(1))) void*)g,
      (__attribute__((address_space(3))) void*)l, 16, 0, 0);
}

template <int N>
__device__ __forceinline__ void wait_vm() {
  static_assert(N == 0 || N == 2 || N == 3 || N == 4 || N == 5 || N == 6 ||
                N == 8 || N == 10 || N == 12 || N == 16, "vmcnt literal");
  if constexpr (N == 0) asm volatile("s_waitcnt vmcnt(0)" ::: "memory");
  else if constexpr (N == 2) asm volatile("s_waitcnt vmcnt(2)" ::: "memory");
  else if constexpr (N == 3) asm volatile("s_waitcnt vmcnt(3)" ::: "memory");
  else if constexpr (N == 4) asm volatile("s_waitcnt vmcnt(4)" ::: "memory");
  else if constexpr (N == 5) asm volatile("s_waitcnt vmcnt(5)" ::: "memory");
  else if constexpr (N == 6) asm volatile("s_waitcnt vmcnt(6)" ::: "memory");
  else if constexpr (N == 8) asm volatile("s_waitcnt vmcnt(8)" ::: "memory");
  else if constexpr (N == 10) asm volatile("s_waitcnt vmcnt(10)" ::: "memory");
  else if constexpr (N == 12) asm volatile("s_waitcnt vmcnt(12)" ::: "memory");
  else asm volatile("s_waitcnt vmcnt(16)" ::: "memory");
}

// ---------------- reductions ----------------
__device__ __forceinline__ float waveAllSum(float v) {
#pragma unroll
  for (int m = 32; m >= 1; m >>= 1) v += __shfl_xor(v, m);
  return v;
}
__device__ __forceinline__ float waveAllMax(float v) {
#pragma unroll
  for (int m = 32; m >= 1; m >>= 1) v = fmaxf(v, __shfl_xor(v, m));
  return v;
}
__device__ __forceinline__ float blockSum(float v, float* red, int nw) {
  v = waveAllSum(v);
  int lane = threadIdx.x & 63, wid = threadIdx.x >> 6;
  __syncthreads();
  if (lane == 0) red[wid] = v;
  __syncthreads();
  float t = 0.f;
  for (int i = 0; i < nw; i++) t += red[i];
  return t;
}
__device__ __forceinline__ float blockMax(float v, float* red, int nw) {
  v = waveAllMax(v);
  int lane = threadIdx.x & 63, wid = threadIdx.x >> 6;
  __syncthreads();
  if (lane == 0) red[wid] = v;
  __syncthreads();
  float t = -INFINITY;
  for (int i = 0; i < nw; i++) t = fmaxf(t, red[i]);
  return t;
}

// ---------------- tables ----------------
__global__ __launch_bounds__(256) void build_C_pp(unsigned short* __restrict__ ch,
                                                  unsigned short* __restrict__ cl) {
  int i = blockIdx.x * 256 + threadIdx.x;
  int t = i >> 10, s = i & 1023;
  int m = (t * s) & 1023;
  float ang = (float)m * 6.135923151542565e-3f;
  float c = cosf(ang);
  unsigned short h = f16h(c);
  ch[i] = h;
  cl[i] = f16h(c - f16tof(h));
}

__global__ void build_filt(float* __restrict__ filt,
                           const float* __restrict__ alpha,
                           const float* __restrict__ fscale) {
  int t = threadIdx.x;
  float fr = (t < 512) ? (float)t : (float)(t - 1024);
  fr *= (1.0f / 1024.0f);
  float km = fmaxf(fabsf(fr), 1e-10f);
  float la = atanf(logf(km));
  for (int l = 0; l < LL; l++) {
    float aa = alpha[l] + fscale[l] * (1.5f - 1.5f);
    filt[l * TS + t] = expf(-aa * la);
  }
}

__global__ void biascat3(const float* __restrict__ qb, const float* __restrict__ kb,
                         const float* __restrict__ vb, float* __restrict__ out) {
  int i = blockIdx.x * 256 + threadIdx.x;  // 0..3071
  const float* s = (i < 1024) ? qb : ((i < 2048) ? kb : vb);
  out[i] = s[i & 1023];
}

// transpose W_el [1024][24] -> W_elT [24][1024]
__global__ __launch_bounds__(256) void trans_wel(const float* __restrict__ W_el,
                                                 float* __restrict__ W_elT) {
  int i = blockIdx.x * 256 + threadIdx.x;   // 0 .. 24*1024-1
  int j = i >> 10, d = i & 1023;
  W_elT[i] = W_el[(size_t)d * NLAT + j];
}

// ---------------- embedding ----------------
__global__ __launch_bounds__(256) void embed_kernel(
    const int* __restrict__ ids, const float* __restrict__ tok_table,
    const float* __restrict__ emb_scales, const float* __restrict__ emb_norm,
    const float* __restrict__ pos_emb, float* __restrict__ x) {
  __shared__ float red[4];
  int row = blockIdx.x;
  int t = row & (TS - 1);
  int tid = threadIdx.x;
  const float* tok = tok_table + (size_t)ids[row] * DM;
  float ev[4];
  float st = 0.f, se = 0.f;
#pragma unroll
  for (int kk = 0; kk < 4; kk++) {
    int d = tid + kk * 256;
    float tv = tok[d];
    float e = tv * emb_scales[d];
    ev[kk] = e;
    st += tv * tv;
    se += e * e;
  }
  st = blockSum(st, red, 4);
  se = blockSum(se, red, 4);
  float sc = sqrtf(st) / (sqrtf(se) + 1e-8f) * emb_norm[0];
  float* xr = x + (size_t)row * DM;
  const float* pr = pos_emb + (size_t)t * DM;
#pragma unroll
  for (int kk = 0; kk < 4; kk++) {
    int d = tid + kk * 256;
    xr[d] = ev[kk] * sc + pr[d];
  }
}

// ---------------- Leech lattice: 1 wave/row, no LDS, no barriers ----------------
__global__ __launch_bounds__(256) void leech_wave(
    float* __restrict__ x, const float* __restrict__ W_elT,
    const float* __restrict__ b_el, const float* __restrict__ W_le,
    const float* __restrict__ b_le, const float* __restrict__ ecs_p,
    const float* __restrict__ epres_p) {
  int tid = threadIdx.x;
  int wv = tid >> 6, lane = tid & 63;
  int row = blockIdx.x * 4 + wv;
  float ecs = ecs_p[0], epres = epres_p[0];
  float* xr = x + (size_t)row * DM;

  float acc[NLAT];
#pragma unroll
  for (int j = 0; j < NLAT; j++) acc[j] = 0.f;
  float sx = 0.f;
  for (int kk = 0; kk < 16; kk++) {
    int d = lane + 64 * kk;
    float v = xr[d];
    sx += v * v;
#pragma unroll
    for (int j = 0; j < NLAT; j++) acc[j] = fmaf(v, W_elT[j * DM + d], acc[j]);
  }
  sx = waveAllSum(sx);
  float ie = sqrtf(sx);
#pragma unroll
  for (int j = 0; j < NLAT; j++) acc[j] = waveAllSum(acc[j]);

  float corr[NLAT];
  float slp = 0.f;
#pragma unroll
  for (int j = 0; j < NLAT; j++) {
    float l = rintf((acc[j] + b_el[j]) / ecs) * ecs;
    acc[j] = l;
    slp = fmaf(l, l, slp);
  }
  float nlp = sqrtf(slp);
  float s1 = ie / (nlp + 1e-8f) * epres;
  float ie2 = fabsf(s1) * nlp;
#pragma unroll
  for (int j = 0; j < NLAT; j++) {
    float e = acc[j] * s1;
    corr[j] = (fabsf(e) > ecs) ? e : 0.f;
  }

  float sd = 0.f;
  for (int kk = 0; kk < 16; kk++) {
    int d = lane + 64 * kk;
    float v = b_le[d];
#pragma unroll
    for (int j = 0; j < NLAT; j++) v = fmaf(corr[j], W_le[j * DM + d], v);
    sd = fmaf(v, v, sd);
  }
  sd = waveAllSum(sd);
  float sc2 = ie2 / (sqrtf(sd) + 1e-8f) * epres;

  for (int kk = 0; kk < 16; kk++) {
    int d = lane + 64 * kk;
    float v = b_le[d];
#pragma unroll
    for (int j = 0; j < NLAT; j++) v = fmaf(corr[j], W_le[j * DM + d], v);
    xr[d] = fmaf(v, sc2, xr[d]);
  }
}

// ---------------- LayerNorm -> f16 hi (+optional lo) planes ----------------
__global__ __launch_bounds__(256) void ln_pp(
    const float* __restrict__ x, const float* __restrict__ w,
    const float* __restrict__ b, unsigned short* __restrict__ oHi,
    unsigned short* __restrict__ oLo, float* __restrict__ hnorm) {
  __shared__ float red[4];
  int row = blockIdx.x, tid = threadIdx.x;
  const float4 v = ((const float4*)(x + (size_t)row * DM))[tid];
  float s = v.x + v.y + v.z + v.w;
  s = blockSum(s, red, 4);
  float mean = s * (1.f / 1024.f);
  float dx = v.x - mean, dy = v.y - mean, dz = v.z - mean, dw = v.w - mean;
  float ss = dx * dx + dy * dy + dz * dz + dw * dw;
  ss = blockSum(ss, red, 4);
  float inv = 1.f / sqrtf(ss * (1.f / 1024.f) + 1e-5f);
  const float4 wv = ((const float4*)w)[tid];
  const float4 bv = ((const float4*)b)[tid];
  float hv[4];
  hv[0] = dx * inv * wv.x + bv.x;
  hv[1] = dy * inv * wv.y + bv.y;
  hv[2] = dz * inv * wv.z + bv.z;
  hv[3] = dw * inv * wv.w + bv.w;
  u16x4 hh;
#pragma unroll
  for (int j = 0; j < 4; j++) hh[j] = f16h(hv[j]);
  *(u16x4*)(oHi + (size_t)row * DM + tid * 4) = hh;
  if (oLo) {
    u16x4 ll;
#pragma unroll
    for (int j = 0; j < 4; j++) ll[j] = f16h(hv[j] - f16tof(hh[j]));
    *(u16x4*)(oLo + (size_t)row * DM + tid * 4) = ll;
  }
  if (hnorm) {
    float hs = hv[0]*hv[0] + hv[1]*hv[1] + hv[2]*hv[2] + hv[3]*hv[3];
    hs = blockSum(hs, red, 4);
    if (tid == 0) hnorm[row] = sqrtf(hs);
  }
}

// ---------------- fp32 -> transposed f16 hi (+optional lo) planes ----------------
__global__ __launch_bounds__(256) void tsplit_f32(
    const float* __restrict__ in, unsigned short* __restrict__ oHi,
    unsigned short* __restrict__ oLo, int ldin, int ldout, float scale) {
  __shared__ float T[64][65];
  int r0 = blockIdx.y * 64, c0 = blockIdx.x * 64;
  int tid = threadIdx.x;
  int r = tid >> 2, s = tid & 3;
  const float* ip = in + (size_t)(r0 + r) * ldin + c0 + s * 16;
#pragma unroll
  for (int q = 0; q < 4; q++) {
    float4 v = ((const float4*)ip)[q];
    T[r][s * 16 + q * 4 + 0] = v.x;
    T[r][s * 16 + q * 4 + 1] = v.y;
    T[r][s * 16 + q * 4 + 2] = v.z;
    T[r][s * 16 + q * 4 + 3] = v.w;
  }
  __syncthreads();
  u16x8 h0, h1, l0, l1;
#pragma unroll
  for (int q = 0; q < 16; q++) {
    float v = T[s * 16 + q][r] * scale;
    unsigned short h = f16h(v);
    if (q < 8) h0[q] = h; else h1[q - 8] = h;
    if (oLo) {
      unsigned short l = f16h(v - f16tof(h));
      if (q < 8) l0[q] = l; else l1[q - 8] = l;
    }
  }
  size_t ob = (size_t)(c0 + r) * ldout + r0 + s * 16;
  *(u16x8*)(oHi + ob) = h0;
  *(u16x8*)(oHi + ob + 8) = h1;
  if (oLo) {
    *(u16x8*)(oLo + ob) = l0;
    *(u16x8*)(oLo + ob + 8) = l1;
  }
}

// ---------------- u16 plane transpose (batched) ----------------
__global__ __launch_bounds__(256) void tsplit_u16(
    const unsigned short* __restrict__ in, unsigned short* __restrict__ out,
    int ldin, int ldout, long sIn, long sOut) {
  __shared__ unsigned short T[64][68];
  int z = blockIdx.z;
  in += (size_t)z * sIn;
  out += (size_t)z * sOut;
  int r0 = blockIdx.y * 64, c0 = blockIdx.x * 64;
  int tid = threadIdx.x;
  int r = tid >> 2, s = tid & 3;
  const unsigned short* ip = in + (size_t)(r0 + r) * ldin + c0 + s * 16;
  u16x8 a = *(const u16x8*)ip;
  u16x8 b = *(const u16x8*)(ip + 8);
#pragma unroll
  for (int q = 0; q < 8; q++) {
    T[r][s * 16 + q] = a[q];
    T[r][s * 16 + 8 + q] = b[q];
  }
  __syncthreads();
  u16x8 o0, o1;
#pragma unroll
  for (int q = 0; q < 8; q++) {
    o0[q] = T[s * 16 + q][r];
    o1[q] = T[s * 16 + 8 + q][r];
  }
  size_t ob = (size_t)(c0 + r) * ldout + r0 + s * 16;
  *(u16x8*)(out + ob) = o0;
  *(u16x8*)(out + ob + 8) = o1;
}

// ---------------- split-f16 MFMA GEMM, TMIx128 tile, BK=NKC*8 ----------------
enum { E_PP = 0, E_QKV, E_F32, E_F32_BIAS, E_P1_GELU, E_F32_ACC_BIAS, E_F32_ATOMIC, E_V, E_P16 };

template <int EPI, bool ALO, bool BLO, int TMI, int DEPTH, int NKC = 4>
__global__ __launch_bounds__(256, 2) void gemmT(
    const unsigned short* __restrict__ Ah, const unsigned short* __restrict__ Al,
    const unsigned short* __restrict__ Bh, const unsigned short* __restrict__ Bl,
    void* __restrict__ C, void* __restrict__ C2, void* __restrict__ C3,
    void* __restrict__ C4, void* __restrict__ C5,
    const float* __restrict__ bias, const float* __restrict__ filtp, float desc,
    int K, int lda, int ldb, int ldc, int zdiv,
    long sAa, long sAb, long sBa, long sBb, long sCa, long sCb) {
  constexpr int NMA = 1 + (ALO ? 1 : 0);
  constexpr int NMB = 1 + (BLO ? 1 : 0);
  constexpr int HA = TMI / 64;
  constexpr int CA = NMA * NKC * HA;
  constexpr int CB = NMB * NKC * 2;
  constexpr int CPW = (CA + CB) / 4;
  constexpr int MI = TMI / 32;
  constexpr int BK = NKC * 8;
  constexpr int NBUF = DEPTH + 1;
  __shared__ __align__(16) unsigned short smA[NBUF][NMA][NKC][TMI][8];
  __shared__ __align__(16) unsigned short smB[NBUF][NMB][NKC][128][8];

  const int gx = gridDim.x, gy = gridDim.y;
  const int nb = gx * gy * gridDim.z;
  const int lid = (blockIdx.z * gy + blockIdx.y) * gx + blockIdx.x;
  const int cpx = nb >> 3;
  const int swz = (lid & 7) * cpx + (lid >> 3);
  const int bxi = swz % gx;
  const int tmp2 = swz / gx;
  const int byi = tmp2 % gy;
  const int bzi = tmp2 / gy;

  const int w = threadIdx.x >> 6, lane = threadIdx.x & 63;
  const int wm = w >> 1, wn = w & 1;
  const int bm = byi * TMI, bn = bxi * 128;
  const int za = bzi / zdiv, zb = bzi % zdiv;
  const long Ao = (long)za * sAa + (long)zb * sAb;
  const long Bo = (long)za * sBa + (long)zb * sBb;

  f32x4 acc[MI][4];
#pragma unroll
  for (int i = 0; i < MI; i++)
#pragma unroll
    for (int j = 0; j < 4; j++) acc[i][j] = (f32x4){0.f, 0.f, 0.f, 0.f};

  auto stage = [&](int buf, int k0) {
#pragma unroll
    for (int c = 0; c < CPW; c++) {
      int id = w + 4 * c;
      if (id < CA) {
        int pl = id / (NKC * HA);
        int rem = id - pl * NKC * HA;
        int kc = rem / HA, half = rem - kc * HA;
        const unsigned short* src =
            (pl ? Al : Ah) + Ao + (size_t)(bm + half * 64 + lane) * lda + k0 + kc * 8;
        gl16(src, (void*)&smA[buf][pl][kc][half * 64][0]);
      } else {
        int bid = id - CA;
        int pl = bid / (NKC * 2);
        int rem = bid - pl * NKC * 2;
        int kc = rem >> 1, half = rem & 1;
        const unsigned short* src =
            (pl ? Bl : Bh) + Bo + (size_t)(bn + half * 64 + lane) * ldb + k0 + kc * 8;
        gl16(src, (void*)&smB[buf][pl][kc][half * 64][0]);
      }
    }
  };

  const int nt = K / BK;
  stage(0, 0);
  if (DEPTH == 2 && nt > 1) stage(1, BK);
  int cur = 0, nxt = (DEPTH == 2) ? 2 : 1;
  for (int t = 0; t < nt; t++) {
    if constexpr (DEPTH == 1) {
      if (t + 1 < nt) {
        stage(nxt, (t + 1) * BK);
        wait_vm<CPW>();
      } else {
        wait_vm<0>();
      }
    } else {
      if (t + 2 < nt) {
        stage(nxt, (t + 2) * BK);
        wait_vm<2 * CPW>();
      } else if (t + 1 < nt) {
        wait_vm<CPW>();
      } else {
        wait_vm<0>();
      }
    }
    __builtin_amdgcn_s_barrier();
    __builtin_amdgcn_sched_barrier(0);

    const int fr = lane & 15, kc2 = lane >> 4;
#pragma unroll
    for (int kb = 0; kb < NKC / 4; kb++) {
      const int kcc = 4 * kb + kc2;
      f16x8 ah[MI], bh[4], alx[MI], blx[4];
#pragma unroll
      for (int i = 0; i < MI; i++) {
        ah[i] = *(const f16x8*)&smA[cur][0][kcc][wm * (TMI / 2) + i * 16 + fr][0];
        if (ALO) alx[i] = *(const f16x8*)&smA[cur][NMA - 1][kcc][wm * (TMI / 2) + i * 16 + fr][0];
      }
#pragma unroll
      for (int j = 0; j < 4; j++) {
        bh[j] = *(const f16x8*)&smB[cur][0][kcc][wn * 64 + j * 16 + fr][0];
        if (BLO) blx[j] = *(const f16x8*)&smB[cur][NMB - 1][kcc][wn * 64 + j * 16 + fr][0];
      }
#pragma unroll
      for (int i = 0; i < MI; i++)
#pragma unroll
        for (int j = 0; j < 4; j++) {
          acc[i][j] = __builtin_amdgcn_mfma_f32_16x16x32_f16(ah[i], bh[j], acc[i][j], 0, 0, 0);
          if (BLO) acc[i][j] = __builtin_amdgcn_mfma_f32_16x16x32_f16(ah[i], blx[j], acc[i][j], 0, 0, 0);
          if (ALO) acc[i][j] = __builtin_amdgcn_mfma_f32_16x16x32_f16(alx[i], bh[j], acc[i][j], 0, 0, 0);
        }
    }
    __builtin_amdgcn_sched_barrier(0);
    __builtin_amdgcn_s_barrier();
    cur = (cur == NBUF - 1) ? 0 : cur + 1;
    nxt = (nxt == NBUF - 1) ? 0 : nxt + 1;
  }

  const int fr0 = lane & 15, rg = lane >> 4;
  const int colb = bn + wn * 64 + fr0;
  const int rowb = bm + wm * (TMI / 2) + rg * 4;
  const long Co = (long)za * sCa + (long)zb * sCb;
#pragma unroll
  for (int i = 0; i < MI; i++)
#pragma unroll
    for (int j = 0; j < 4; j++)
#pragma unroll
      for (int r = 0; r < 4; r++) {
        int row = rowb + i * 16 + r;
        int col = colb + j * 16;
        float v = acc[i][j][r] * desc;
        long idx = Co + (long)row * ldc + col;
        if constexpr (EPI == E_PP) {
          unsigned short h = f16h(v);
          ((unsigned short*)C)[idx] = h;
          ((unsigned short*)C2)[idx] = f16h(v - f16tof(h));
        } else if constexpr (EPI == E_QKV) {
          int t2 = row & (TS - 1);
          v *= filtp[t2];
          if (t2 == 0) v = fmaf(1024.f * filtp[0], bias[col], v);
          int seg = col >> 10, nn = col & 1023;
          long oix = (long)row * 1024 + nn;
          if (seg == 0) {
            unsigned short h = f16h(v);
            ((unsigned short*)C)[oix] = h;
            ((unsigned short*)C2)[oix] = f16h(v - f16tof(h));
          } else {
            unsigned short h = f16h(v);
            ((unsigned short*)C3)[oix] = h;
            ((unsigned short*)C4)[oix] = f16h(v - f16tof(h));
          }
        } else if constexpr (EPI == E_V) {
          int t2 = row & (TS - 1);
          v *= filtp[t2];
          if (t2 == 0) v = fmaf(1024.f * filtp[0], bias[col], v);
          ((unsigned short*)C)[idx] = f16h(v);
        } else if constexpr (EPI == E_P16) {
          ((unsigned short*)C)[idx] = f16h(v);
        } else if constexpr (EPI == E_F32) {
          ((float*)C)[idx] = v;
        } else if constexpr (EPI == E_F32_BIAS) {
          ((float*)C)[idx] = v + bias[col];
        } else if constexpr (EPI == E_P1_GELU) {
          v += bias[col];
          v = 0.5f * v * (1.f + erff(v * 0.7071067811865476f));
          ((unsigned short*)C)[idx] = f16h(v);
        } else if constexpr (EPI == E_F32_ACC_BIAS) {
          ((float*)C)[idx] += v + bias[col];
        } else {  // E_F32_ATOMIC
          if (za == 0) v += bias[col];
          atomicAdd(&((float*)C)[(long)row * ldc + col], v);
        }
      }
}

// ---------------- softmax -> f16 plane ----------------
__global__ __launch_bounds__(256) void softmax_p(const float* __restrict__ S,
                                                 unsigned short* __restrict__ P,
                                                 float scale) {
  __shared__ float red[4];
  int row = blockIdx.x, tid = threadIdx.x;
  float4 v = ((const float4*)(S + (size_t)row * 1024))[tid];
  v.x *= scale; v.y *= scale; v.z *= scale; v.w *= scale;
  float m = fmaxf(fmaxf(v.x, v.y), fmaxf(v.z, v.w));
  m = blockMax(m, red, 4);
  float4 e;
  e.x = expf(v.x - m); e.y = expf(v.y - m); e.z = expf(v.z - m); e.w = expf(v.w - m);
  float s = e.x + e.y + e.z + e.w;
  s = blockSum(s, red, 4);
  float inv = 1.f / s;
  u16x4 o;
  o[0] = f16h(e.x * inv); o[1] = f16h(e.y * inv);
  o[2] = f16h(e.z * inv); o[3] = f16h(e.w * inv);
  *(u16x4*)(P + (size_t)row * 1024 + tid * 4) = o;
}

// ---------------- out-scale + residual ----------------
__global__ __launch_bounds__(256) void outscale_kernel(
    float* __restrict__ x, const float* __restrict__ outp,
    const float* __restrict__ hnorm, const float* __restrict__ enorm_l) {
  __shared__ float red[4];
  int row = blockIdx.x, tid = threadIdx.x;
  float4 v = ((const float4*)(outp + (size_t)row * DM))[tid];
  float ss = v.x * v.x + v.y * v.y + v.z * v.z + v.w * v.w;
  ss = blockSum(ss, red, 4);
  float sc = hnorm[row] / (sqrtf(ss) + 1e-8f) * enorm_l[0];
  float4* xp = (float4*)(x + (size_t)row * DM);
  float4 xv = xp[tid];
  xv.x = fmaf(v.x, sc, xv.x);
  xv.y = fmaf(v.y, sc, xv.y);
  xv.z = fmaf(v.z, sc, xv.z);
  xv.w = fmaf(v.w, sc, xv.w);
  xp[tid] = xv;
}

// ---------------- two-stage mean-pool + classifier ----------------
__global__ __launch_bounds__(256) void pool_partial(const float* __restrict__ x,
                                                    float* __restrict__ part) {
  int b = blockIdx.x, c = blockIdx.y, tid = threadIdx.x;
  const float* xb = x + ((size_t)b * TS + c * 64) * DM;
  float4 s = {0.f, 0.f, 0.f, 0.f};
  for (int r = 0; r < 64; r++) {
    float4 v = ((const float4*)(xb + (size_t)r * DM))[tid];
    s.x += v.x; s.y += v.y; s.z += v.z; s.w += v.w;
  }
  ((float4*)(part + (size_t)(b * 16 + c) * DM))[tid] = s;
}
__global__ __launch_bounds__(1024) void pool_cls2(const float* __restrict__ part,
                                                  const float* __restrict__ clsW,
                                                  const float* __restrict__ clsb,
                                                  float* __restrict__ out) {
  __shared__ float red[16];
  int b = blockIdx.x, d = threadIdx.x;
  float s = 0.f;
  for (int c = 0; c < 16; c++) s += part[(size_t)(b * 16 + c) * DM + d];
  float p = s * (1.f / 1024.f);
  float a0 = p * clsW[d * 2 + 0];
  float a1 = p * clsW[d * 2 + 1];
  a0 = blockSum(a0, red, 16);
  a1 = blockSum(a1, red, 16);
  if (d == 0) {
    out[b * 2 + 0] = a0 + clsb[0];
    out[b * 2 + 1] = a1 + clsb[1];
  }
}

// ---------------- driver ----------------
extern "C" void kernel_launch(void* const* d_in, const int* in_sizes, int n_in,
                              void* d_out, int out_size, void* d_ws, size_t ws_size,
                              hipStream_t stream) {
  (void)in_sizes; (void)n_in; (void)out_size; (void)ws_size;
  const int*   ids        = (const int*)  d_in[0];
  const float* tok_table  = (const float*)d_in[1];
  const float* emb_scales = (const float*)d_in[2];
  const float* emb_norm   = (const float*)d_in[3];
  const float* pos_emb    = (const float*)d_in[4];
  const float* W_el       = (const float*)d_in[5];
  const float* b_el       = (const float*)d_in[6];
  const float* W_le       = (const float*)d_in[7];
  const float* b_le       = (const float*)d_in[8];
  const float* ecs        = (const float*)d_in[9];
  const float* epres      = (const float*)d_in[10];
  const float* ln1_w      = (const float*)d_in[11];
  const float* ln1_b      = (const float*)d_in[12];
  const float* ln2_w      = (const float*)d_in[13];
  const float* ln2_b      = (const float*)d_in[14];
  const float* qW = (const float*)d_in[15]; const float* qb = (const float*)d_in[16];
  const float* kW = (const float*)d_in[17]; const float* kb = (const float*)d_in[18];
  const float* vW = (const float*)d_in[19]; const float* vb = (const float*)d_in[20];
  const float* oW = (const float*)d_in[21]; const float* ob = (const float*)d_in[22];
  const float* f1W = (const float*)d_in[23]; const float* f1b = (const float*)d_in[24];
  const float* f2W = (const float*)d_in[25]; const float* f2b = (const float*)d_in[26];
  const float* alpha  = (const float*)d_in[27];
  const float* fscale = (const float*)d_in[28];
  const float* enorm  = (const float*)d_in[29];
  const float* clsW   = (const float*)d_in[30];
  const float* clsb   = (const float*)d_in[31];

  const size_t MB = 1u << 20;
  const long M1 = 1048576;
  char* p = (char*)d_ws;
  auto take = [&](size_t n) { char* r = p; p += n; return r; };
  unsigned short* CtH = (unsigned short*)take(2 * MB);
  unsigned short* CtL = (unsigned short*)take(2 * MB);
  float* filt    = (float*)take(16 * 1024);
  float* hnorm   = (float*)take(16 * 1024);
  float* bias3   = (float*)take(16 * 1024);
  float* W_elT   = (float*)take(128 * 1024);
  float* part    = (float*)take(1 * MB);
  float* x       = (float*)take(16 * MB);
  unsigned short* BIG = (unsigned short*)take(64 * MB);
  unsigned short* Hh  = BIG,            *Hl  = BIG + 4 * M1;
  unsigned short* HTh = BIG + 8 * M1,   *HTl = BIG + 12 * M1;
  unsigned short* HCh = BIG + 16 * M1,  *HCl = BIG + 20 * M1;
  unsigned short* WTh = BIG + 24 * M1,  *WTl = BIG + 28 * M1;
  unsigned short* P   = BIG;
  unsigned short* QFh = (unsigned short*)take(8 * MB);
  unsigned short* QFl = (unsigned short*)take(8 * MB);
  unsigned short* KFh = (unsigned short*)take(8 * MB);
  unsigned short* KFl = (unsigned short*)take(8 * MB);
  unsigned short* VT  = (unsigned short*)take(8 * MB);
  float* SREG = (float*)take(32 * MB);
  unsigned short* atth = (unsigned short*)SREG;
  float* OUTP = SREG + 4 * M1;
  unsigned short* MID = (unsigned short*)SREG;
  unsigned short* Vtmp = HTh;

  const float WS = 1024.f;
  const float DS = 1.f / 1024.f;
  const float scale = 0.08838834764831845f;

  build_C_pp<<<4096, 256, 0, stream>>>(CtH, CtL);
  build_filt<<<1, 1024, 0, stream>>>(filt, alpha, fscale);
  trans_wel<<<96, 256, 0, stream>>>(W_el, W_elT);
  embed_kernel<<<NROWS, 256, 0, stream>>>(ids, tok_table, emb_scales, emb_norm, pos_emb, x);
  leech_wave<<<1024, 256, 0, stream>>>(x, W_elT, b_el, W_le, b_le, ecs, epres);

  dim3 t44(16, 16, 4), t11(16, 16, 1);
  for (int i = 0; i < LL; i++) {
    ln_pp<<<NROWS, 256, 0, stream>>>(x, ln1_w + i * DM, ln1_b + i * DM, Hh, Hl, hnorm);
    tsplit_u16<<<dim3(16, 16, 8), 256, 0, stream>>>(Hh, HTh, 1024, 1024, M1, M1);
    gemmT<E_PP, true, true, 64, 2><<<dim3(8, 16, 4), 256, 0, stream>>>(
        CtH, CtL, HTh, HTl, HCh, HCl, nullptr, nullptr, nullptr,
        nullptr, nullptr, 1.f, 1024, 1024, 1024, 1024, 1, 0, 0, M1, 0, M1, 0);
    tsplit_f32<<<t11, 256, 0, stream>>>(qW + (size_t)i * M1, WTh, WTl, 1024, 1024, WS);
    tsplit_f32<<<t11, 256, 0, stream>>>(kW + (size_t)i * M1, WTh + M1, WTl + M1, 1024, 1024, WS);
    tsplit_f32<<<t11, 256, 0, stream>>>(vW + (size_t)i * M1, WTh + 2 * M1, nullptr, 1024, 1024, WS);
    biascat3<<<12, 256, 0, stream>>>(qb + i * DM, kb + i * DM, vb + i * DM, bias3);
    gemmT<E_QKV, true, true, 128, 1><<<dim3(16, 32, 1), 256, 0, stream>>>(
        HCh, HCl, WTh, WTl, QFh, QFl, KFh, KFl, nullptr,
        bias3, filt + i * TS, DS, 1024, 1024, 1024, 1024, 1, 0, 0, 0, 0, 0, 0);
    gemmT<E_V, false, false, 64, 2><<<dim3(8, 64, 1), 256, 0, stream>>>(
        HCh, nullptr, WTh + 2 * M1, nullptr, Vtmp, nullptr, nullptr, nullptr, nullptr,
        vb + i * DM, filt + i * TS, DS, 1024, 1024, 1024, 1024, 1, 0, 0, 0, 0, 0, 0);
    tsplit_u16<<<t44, 256, 0, stream>>>(Vtmp, VT, 1024, 1024, M1, M1);
    // attention: QKT per b at TMI=128 (round-14 optimum); softmax; batched PV (f16-only)
    for (int b = 0; b < BB; b++) {
      gemmT<E_F32, true, true, 128, 1><<<dim3(8, 8, 8), 256, 0, stream>>>(
          QFh + (size_t)b * M1, QFl + (size_t)b * M1,
          KFh + (size_t)b * M1, KFl + (size_t)b * M1,
          SREG, nullptr, nullptr, nullptr, nullptr,
          nullptr, nullptr, 1.f, 128, 1024, 1024, 1024, 1, 128, 0, 128, 0, M1, 0);
      softmax_p<<<HH * TS, 256, 0, stream>>>(SREG, P + (size_t)b * 8 * M1, scale);
    }
    gemmT<E_P16, false, false, 64, 2><<<dim3(1, 16, 32), 256, 0, stream>>>(
        P, nullptr, VT, nullptr, atth, nullptr, nullptr, nullptr, nullptr,
        nullptr, nullptr, 1.f, 1024, 1024, 1024, 1024, 8,
        8L * M1, M1, M1, 131072, M1, 128);
    // o-proj: 1-term, TMI=64, DEPTH=2, no split-K -> direct f32+bias store
    tsplit_f32<<<t11, 256, 0, stream>>>(oW + (size_t)i * M1, WTh, nullptr, 1024, 1024, WS);
    gemmT<E_F32_BIAS, false, false, 64, 2><<<dim3(8, 64, 1), 256, 0, stream>>>(
        atth, nullptr, WTh, nullptr, OUTP, nullptr, nullptr, nullptr, nullptr,
        ob + i * DM, nullptr, DS, 1024, 1024, 1024, 1024, 1, 0, 0, 0, 0, 0, 0);
    outscale_kernel<<<NROWS, 256, 0, stream>>>(x, OUTP, hnorm, enorm + i);
    // FFN (round-14 optimum configs)
    ln_pp<<<NROWS, 256, 0, stream>>>(x, ln2_w + i * DM, ln2_b + i * DM, Hh, nullptr, nullptr);
    tsplit_f32<<<dim3(64, 16, 1), 256, 0, stream>>>(f1W + (size_t)i * 4 * M1, WTh, nullptr, 4096, 1024, WS);
    gemmT<E_P1_GELU, false, false, 128, 1, 8><<<dim3(32, 32, 1), 256, 0, stream>>>(
        Hh, nullptr, WTh, nullptr, MID, nullptr, nullptr, nullptr, nullptr,
        f1b + i * DFF, nullptr, DS, 1024, 1024, 1024, 4096, 1, 0, 0, 0, 0, 0, 0);
    tsplit_f32<<<dim3(16, 64, 1), 256, 0, stream>>>(f2W + (size_t)i * 4 * M1, WTh, nullptr, 1024, 4096, WS);
    gemmT<E_F32_ATOMIC, false, false, 128, 1, 8><<<dim3(8, 32, 2), 256, 0, stream>>>(
        MID, nullptr, WTh, nullptr, x, nullptr, nullptr, nullptr, nullptr,
        f2b + i * DM, nullptr, DS, 2048, 4096, 4096, 1024, 1, 2048, 0, 2048, 0, 0, 0);
  }
  pool_partial<<<dim3(BB, 16), 256, 0, stream>>>(x, part);
  pool_cls2<<<BB, 1024, 0, stream>>>(part, clsW, clsb, (float*)d_out);
}

// Round 18
// 1807.668 us; speedup vs baseline: 1.1379x; 1.0065x over previous
//
#include <hip/hip_runtime.h>
#include <math.h>

#define TS    1024
#define DM    1024
#define BB    4
#define HH    8
#define LL    3
#define NLAT  24
#define NROWS 4096
#define DFF   4096

typedef _Float16 f16x8 __attribute__((ext_vector_type(8)));
typedef float f32x4 __attribute__((ext_vector_type(4)));
typedef unsigned short u16x4 __attribute__((ext_vector_type(4)));
typedef unsigned short u16x8 __attribute__((ext_vector_type(8)));

__device__ __forceinline__ unsigned short f16h(float x) {
  _Float16 h = (_Float16)x;
  return __builtin_bit_cast(unsigned short, h);
}
__device__ __forceinline__ float f16tof(unsigned short u) {
  _Float16 h = __builtin_bit_cast(_Float16, u);
  return (float)h;
}
__device__ __forceinline__ void gl16(const void* g, void* l) {
  __builtin_amdgcn_global_load_lds(
      (const __attribute__((address_space(1))) void*)g,
      (__attribute__((address_space(3))) void*)l, 16, 0, 0);
}

template <int N>
__device__ __forceinline__ void wait_vm() {
  static_assert(N == 0 || N == 2 || N == 3 || N == 4 || N == 5 || N == 6 ||
                N == 8 || N == 10 || N == 12 || N == 16, "vmcnt literal");
  if constexpr (N == 0) asm volatile("s_waitcnt vmcnt(0)" ::: "memory");
  else if constexpr (N == 2) asm volatile("s_waitcnt vmcnt(2)" ::: "memory");
  else if constexpr (N == 3) asm volatile("s_waitcnt vmcnt(3)" ::: "memory");
  else if constexpr (N == 4) asm volatile("s_waitcnt vmcnt(4)" ::: "memory");
  else if constexpr (N == 5) asm volatile("s_waitcnt vmcnt(5)" ::: "memory");
  else if constexpr (N == 6) asm volatile("s_waitcnt vmcnt(6)" ::: "memory");
  else if constexpr (N == 8) asm volatile("s_waitcnt vmcnt(8)" ::: "memory");
  else if constexpr (N == 10) asm volatile("s_waitcnt vmcnt(10)" ::: "memory");
  else if constexpr (N == 12) asm volatile("s_waitcnt vmcnt(12)" ::: "memory");
  else asm volatile("s_waitcnt vmcnt(16)" ::: "memory");
}

// ---------------- reductions ----------------
__device__ __forceinline__ float waveAllSum(float v) {
#pragma unroll
  for (int m = 32; m >= 1; m >>= 1) v += __shfl_xor(v, m);
  return v;
}
__device__ __forceinline__ float waveAllMax(float v) {
#pragma unroll
  for (int m = 32; m >= 1; m >>= 1) v = fmaxf(v, __shfl_xor(v, m));
  return v;
}
__device__ __forceinline__ float blockSum(float v, float* red, int nw) {
  v = waveAllSum(v);
  int lane = threadIdx.x & 63, wid = threadIdx.x >> 6;
  __syncthreads();
  if (lane == 0) red[wid] = v;
  __syncthreads();
  float t = 0.f;
  for (int i = 0; i < nw; i++) t += red[i];
  return t;
}
__device__ __forceinline__ float blockMax(float v, float* red, int nw) {
  v = waveAllMax(v);
  int lane = threadIdx.x & 63, wid = threadIdx.x >> 6;
  __syncthreads();
  if (lane == 0) red[wid] = v;
  __syncthreads();
  float t = -INFINITY;
  for (int i = 0; i < nw; i++) t = fmaxf(t, red[i]);
  return t;
}

// ---------------- tables ----------------
__global__ __launch_bounds__(256) void build_C_pp(unsigned short* __restrict__ ch,
                                                  unsigned short* __restrict__ cl) {
  int i = blockIdx.x * 256 + threadIdx.x;
  int t = i >> 10, s = i & 1023;
  int m = (t * s) & 1023;
  float ang = (float)m * 6.135923151542565e-3f;
  float c = cosf(ang);
  unsigned short h = f16h(c);
  ch[i] = h;
  cl[i] = f16h(c - f16tof(h));
}

__global__ void build_filt(float* __restrict__ filt,
                           const float* __restrict__ alpha,
                           const float* __restrict__ fscale) {
  int t = threadIdx.x;
  float fr = (t < 512) ? (float)t : (float)(t - 1024);
  fr *= (1.0f / 1024.0f);
  float km = fmaxf(fabsf(fr), 1e-10f);
  float la = atanf(logf(km));
  for (int l = 0; l < LL; l++) {
    float aa = alpha[l] + fscale[l] * (1.5f - 1.5f);
    filt[l * TS + t] = expf(-aa * la);
  }
}

// all 3 layers' q/k/v bias concat in one launch: out[l][0:3072]
__global__ void biascat3_all(const float* __restrict__ qb, const float* __restrict__ kb,
                             const float* __restrict__ vb, float* __restrict__ out) {
  int i = blockIdx.x * 256 + threadIdx.x;  // 0 .. 3*3072-1
  int l = i / 3072, r = i - l * 3072;
  const float* s = (r < 1024) ? (qb + l * DM) : ((r < 2048) ? (kb + l * DM) : (vb + l * DM));
  out[i] = s[r & 1023];
}

// transpose W_el [1024][24] -> W_elT [24][1024]
__global__ __launch_bounds__(256) void trans_wel(const float* __restrict__ W_el,
                                                 float* __restrict__ W_elT) {
  int i = blockIdx.x * 256 + threadIdx.x;   // 0 .. 24*1024-1
  int j = i >> 10, d = i & 1023;
  W_elT[i] = W_el[(size_t)d * NLAT + j];
}

// ---------------- embedding ----------------
__global__ __launch_bounds__(256) void embed_kernel(
    const int* __restrict__ ids, const float* __restrict__ tok_table,
    const float* __restrict__ emb_scales, const float* __restrict__ emb_norm,
    const float* __restrict__ pos_emb, float* __restrict__ x) {
  __shared__ float red[4];
  int row = blockIdx.x;
  int t = row & (TS - 1);
  int tid = threadIdx.x;
  const float* tok = tok_table + (size_t)ids[row] * DM;
  float ev[4];
  float st = 0.f, se = 0.f;
#pragma unroll
  for (int kk = 0; kk < 4; kk++) {
    int d = tid + kk * 256;
    float tv = tok[d];
    float e = tv * emb_scales[d];
    ev[kk] = e;
    st += tv * tv;
    se += e * e;
  }
  st = blockSum(st, red, 4);
  se = blockSum(se, red, 4);
  float sc = sqrtf(st) / (sqrtf(se) + 1e-8f) * emb_norm[0];
  float* xr = x + (size_t)row * DM;
  const float* pr = pos_emb + (size_t)t * DM;
#pragma unroll
  for (int kk = 0; kk < 4; kk++) {
    int d = tid + kk * 256;
    xr[d] = ev[kk] * sc + pr[d];
  }
}

// ---------------- Leech lattice: 1 wave/row, no LDS, no barriers ----------------
__global__ __launch_bounds__(256) void leech_wave(
    float* __restrict__ x, const float* __restrict__ W_elT,
    const float* __restrict__ b_el, const float* __restrict__ W_le,
    const float* __restrict__ b_le, const float* __restrict__ ecs_p,
    const float* __restrict__ epres_p) {
  int tid = threadIdx.x;
  int wv = tid >> 6, lane = tid & 63;
  int row = blockIdx.x * 4 + wv;
  float ecs = ecs_p[0], epres = epres_p[0];
  float* xr = x + (size_t)row * DM;

  float acc[NLAT];
#pragma unroll
  for (int j = 0; j < NLAT; j++) acc[j] = 0.f;
  float sx = 0.f;
  for (int kk = 0; kk < 16; kk++) {
    int d = lane + 64 * kk;
    float v = xr[d];
    sx += v * v;
#pragma unroll
    for (int j = 0; j < NLAT; j++) acc[j] = fmaf(v, W_elT[j * DM + d], acc[j]);
  }
  sx = waveAllSum(sx);
  float ie = sqrtf(sx);
#pragma unroll
  for (int j = 0; j < NLAT; j++) acc[j] = waveAllSum(acc[j]);

  float corr[NLAT];
  float slp = 0.f;
#pragma unroll
  for (int j = 0; j < NLAT; j++) {
    float l = rintf((acc[j] + b_el[j]) / ecs) * ecs;
    acc[j] = l;
    slp = fmaf(l, l, slp);
  }
  float nlp = sqrtf(slp);
  float s1 = ie / (nlp + 1e-8f) * epres;
  float ie2 = fabsf(s1) * nlp;
#pragma unroll
  for (int j = 0; j < NLAT; j++) {
    float e = acc[j] * s1;
    corr[j] = (fabsf(e) > ecs) ? e : 0.f;
  }

  float sd = 0.f;
  for (int kk = 0; kk < 16; kk++) {
    int d = lane + 64 * kk;
    float v = b_le[d];
#pragma unroll
    for (int j = 0; j < NLAT; j++) v = fmaf(corr[j], W_le[j * DM + d], v);
    sd = fmaf(v, v, sd);
  }
  sd = waveAllSum(sd);
  float sc2 = ie2 / (sqrtf(sd) + 1e-8f) * epres;

  for (int kk = 0; kk < 16; kk++) {
    int d = lane + 64 * kk;
    float v = b_le[d];
#pragma unroll
    for (int j = 0; j < NLAT; j++) v = fmaf(corr[j], W_le[j * DM + d], v);
    xr[d] = fmaf(v, sc2, xr[d]);
  }
}

// ---------------- LayerNorm -> f16 hi (+optional lo) planes ----------------
__global__ __launch_bounds__(256) void ln_pp(
    const float* __restrict__ x, const float* __restrict__ w,
    const float* __restrict__ b, unsigned short* __restrict__ oHi,
    unsigned short* __restrict__ oLo, float* __restrict__ hnorm) {
  __shared__ float red[4];
  int row = blockIdx.x, tid = threadIdx.x;
  const float4 v = ((const float4*)(x + (size_t)row * DM))[tid];
  float s = v.x + v.y + v.z + v.w;
  s = blockSum(s, red, 4);
  float mean = s * (1.f / 1024.f);
  float dx = v.x - mean, dy = v.y - mean, dz = v.z - mean, dw = v.w - mean;
  float ss = dx * dx + dy * dy + dz * dz + dw * dw;
  ss = blockSum(ss, red, 4);
  float inv = 1.f / sqrtf(ss * (1.f / 1024.f) + 1e-5f);
  const float4 wv = ((const float4*)w)[tid];
  const float4 bv = ((const float4*)b)[tid];
  float hv[4];
  hv[0] = dx * inv * wv.x + bv.x;
  hv[1] = dy * inv * wv.y + bv.y;
  hv[2] = dz * inv * wv.z + bv.z;
  hv[3] = dw * inv * wv.w + bv.w;
  u16x4 hh;
#pragma unroll
  for (int j = 0; j < 4; j++) hh[j] = f16h(hv[j]);
  *(u16x4*)(oHi + (size_t)row * DM + tid * 4) = hh;
  if (oLo) {
    u16x4 ll;
#pragma unroll
    for (int j = 0; j < 4; j++) ll[j] = f16h(hv[j] - f16tof(hh[j]));
    *(u16x4*)(oLo + (size_t)row * DM + tid * 4) = ll;
  }
  if (hnorm) {
    float hs = hv[0]*hv[0] + hv[1]*hv[1] + hv[2]*hv[2] + hv[3]*hv[3];
    hs = blockSum(hs, red, 4);
    if (tid == 0) hnorm[row] = sqrtf(hs);
  }
}

// ---------------- fused out-scale + residual + LayerNorm2 -> f16 hi plane ----------------
// Bitwise-equivalent to outscale_kernel followed by ln_pp(x, ln2_w, ln2_b, Hh, null, null):
// the updated x row is kept in registers for the LN pass (saves a 16MB x re-read + launch).
__global__ __launch_bounds__(256) void outscale_ln(
    float* __restrict__ x, const float* __restrict__ outp,
    const float* __restrict__ hnorm, const float* __restrict__ enorm_l,
    const float* __restrict__ w, const float* __restrict__ b,
    unsigned short* __restrict__ oHi) {
  __shared__ float red[4];
  int row = blockIdx.x, tid = threadIdx.x;
  float4 v = ((const float4*)(outp + (size_t)row * DM))[tid];
  float ss = v.x * v.x + v.y * v.y + v.z * v.z + v.w * v.w;
  ss = blockSum(ss, red, 4);
  float sc = hnorm[row] / (sqrtf(ss) + 1e-8f) * enorm_l[0];
  float4* xp = (float4*)(x + (size_t)row * DM);
  float4 xv = xp[tid];
  xv.x = fmaf(v.x, sc, xv.x);
  xv.y = fmaf(v.y, sc, xv.y);
  xv.z = fmaf(v.z, sc, xv.z);
  xv.w = fmaf(v.w, sc, xv.w);
  xp[tid] = xv;
  // LN of the updated row (identical math to ln_pp)
  float s = xv.x + xv.y + xv.z + xv.w;
  s = blockSum(s, red, 4);
  float mean = s * (1.f / 1024.f);
  float dx = xv.x - mean, dy = xv.y - mean, dz = xv.z - mean, dw = xv.w - mean;
  float s2 = dx * dx + dy * dy + dz * dz + dw * dw;
  s2 = blockSum(s2, red, 4);
  float inv = 1.f / sqrtf(s2 * (1.f / 1024.f) + 1e-5f);
  const float4 wv = ((const float4*)w)[tid];
  const float4 bv = ((const float4*)b)[tid];
  u16x4 hh;
  hh[0] = f16h(dx * inv * wv.x + bv.x);
  hh[1] = f16h(dy * inv * wv.y + bv.y);
  hh[2] = f16h(dz * inv * wv.z + bv.z);
  hh[3] = f16h(dw * inv * wv.w + bv.w);
  *(u16x4*)(oHi + (size_t)row * DM + tid * 4) = hh;
}

// ---------------- fp32 -> transposed f16 hi (+optional lo) planes ----------------
__global__ __launch_bounds__(256) void tsplit_f32(
    const float* __restrict__ in, unsigned short* __restrict__ oHi,
    unsigned short* __restrict__ oLo, int ldin, int ldout, float scale) {
  __shared__ float T[64][65];
  int r0 = blockIdx.y * 64, c0 = blockIdx.x * 64;
  int tid = threadIdx.x;
  int r = tid >> 2, s = tid & 3;
  const float* ip = in + (size_t)(r0 + r) * ldin + c0 + s * 16;
#pragma unroll
  for (int q = 0; q < 4; q++) {
    float4 v = ((const float4*)ip)[q];
    T[r][s * 16 + q * 4 + 0] = v.x;
    T[r][s * 16 + q * 4 + 1] = v.y;
    T[r][s * 16 + q * 4 + 2] = v.z;
    T[r][s * 16 + q * 4 + 3] = v.w;
  }
  __syncthreads();
  u16x8 h0, h1, l0, l1;
#pragma unroll
  for (int q = 0; q < 16; q++) {
    float v = T[s * 16 + q][r] * scale;
    unsigned short h = f16h(v);
    if (q < 8) h0[q] = h; else h1[q - 8] = h;
    if (oLo) {
      unsigned short l = f16h(v - f16tof(h));
      if (q < 8) l0[q] = l; else l1[q - 8] = l;
    }
  }
  size_t ob = (size_t)(c0 + r) * ldout + r0 + s * 16;
  *(u16x8*)(oHi + ob) = h0;
  *(u16x8*)(oHi + ob + 8) = h1;
  if (oLo) {
    *(u16x8*)(oLo + ob) = l0;
    *(u16x8*)(oLo + ob + 8) = l1;
  }
}

// ---------------- u16 plane transpose (batched) ----------------
__global__ __launch_bounds__(256) void tsplit_u16(
    const unsigned short* __restrict__ in, unsigned short* __restrict__ out,
    int ldin, int ldout, long sIn, long sOut) {
  __shared__ unsigned short T[64][68];
  int z = blockIdx.z;
  in += (size_t)z * sIn;
  out += (size_t)z * sOut;
  int r0 = blockIdx.y * 64, c0 = blockIdx.x * 64;
  int tid = threadIdx.x;
  int r = tid >> 2, s = tid & 3;
  const unsigned short* ip = in + (size_t)(r0 + r) * ldin + c0 + s * 16;
  u16x8 a = *(const u16x8*)ip;
  u16x8 b = *(const u16x8*)(ip + 8);
#pragma unroll
  for (int q = 0; q < 8; q++) {
    T[r][s * 16 + q] = a[q];
    T[r][s * 16 + 8 + q] = b[q];
  }
  __syncthreads();
  u16x8 o0, o1;
#pragma unroll
  for (int q = 0; q < 8; q++) {
    o0[q] = T[s * 16 + q][r];
    o1[q] = T[s * 16 + 8 + q][r];
  }
  size_t ob = (size_t)(c0 + r) * ldout + r0 + s * 16;
  *(u16x8*)(out + ob) = o0;
  *(u16x8*)(out + ob + 8) = o1;
}

// ---------------- split-f16 MFMA GEMM, TMIx128 tile, BK=NKC*8 ----------------
enum { E_PP = 0, E_QKV, E_F32, E_F32_BIAS, E_P1_GELU, E_F32_ACC_BIAS, E_F32_ATOMIC, E_V, E_P16 };

template <int EPI, bool ALO, bool BLO, int TMI, int DEPTH, int NKC = 4>
__global__ __launch_bounds__(256, 2) void gemmT(
    const unsigned short* __restrict__ Ah, const unsigned short* __restrict__ Al,
    const unsigned short* __restrict__ Bh, const unsigned short* __restrict__ Bl,
    void* __restrict__ C, void* __restrict__ C2, void* __restrict__ C3,
    void* __restrict__ C4, void* __restrict__ C5,
    const float* __restrict__ bias, const float* __restrict__ filtp, float desc,
    int K, int lda, int ldb, int ldc, int zdiv,
    long sAa, long sAb, long sBa, long sBb, long sCa, long sCb) {
  constexpr int NMA = 1 + (ALO ? 1 : 0);
  constexpr int NMB = 1 + (BLO ? 1 : 0);
  constexpr int HA = TMI / 64;
  constexpr int CA = NMA * NKC * HA;
  constexpr int CB = NMB * NKC * 2;
  constexpr int CPW = (CA + CB) / 4;
  constexpr int MI = TMI / 32;
  constexpr int BK = NKC * 8;
  constexpr int NBUF = DEPTH + 1;
  __shared__ __align__(16) unsigned short smA[NBUF][NMA][NKC][TMI][8];
  __shared__ __align__(16) unsigned short smB[NBUF][NMB][NKC][128][8];

  const int gx = gridDim.x, gy = gridDim.y;
  const int nb = gx * gy * gridDim.z;
  const int lid = (blockIdx.z * gy + blockIdx.y) * gx + blockIdx.x;
  const int cpx = nb >> 3;
  const int swz = (lid & 7) * cpx + (lid >> 3);
  const int bxi = swz % gx;
  const int tmp2 = swz / gx;
  const int byi = tmp2 % gy;
  const int bzi = tmp2 / gy;

  const int w = threadIdx.x >> 6, lane = threadIdx.x & 63;
  const int wm = w >> 1, wn = w & 1;
  const int bm = byi * TMI, bn = bxi * 128;
  const int za = bzi / zdiv, zb = bzi % zdiv;
  const long Ao = (long)za * sAa + (long)zb * sAb;
  const long Bo = (long)za * sBa + (long)zb * sBb;

  f32x4 acc[MI][4];
#pragma unroll
  for (int i = 0; i < MI; i++)
#pragma unroll
    for (int j = 0; j < 4; j++) acc[i][j] = (f32x4){0.f, 0.f, 0.f, 0.f};

  auto stage = [&](int buf, int k0) {
#pragma unroll
    for (int c = 0; c < CPW; c++) {
      int id = w + 4 * c;
      if (id < CA) {
        int pl = id / (NKC * HA);
        int rem = id - pl * NKC * HA;
        int kc = rem / HA, half = rem - kc * HA;
        const unsigned short* src =
            (pl ? Al : Ah) + Ao + (size_t)(bm + half * 64 + lane) * lda + k0 + kc * 8;
        gl16(src, (void*)&smA[buf][pl][kc][half * 64][0]);
      } else {
        int bid = id - CA;
        int pl = bid / (NKC * 2);
        int rem = bid - pl * NKC * 2;
        int kc = rem >> 1, half = rem & 1;
        const unsigned short* src =
            (pl ? Bl : Bh) + Bo + (size_t)(bn + half * 64 + lane) * ldb + k0 + kc * 8;
        gl16(src, (void*)&smB[buf][pl][kc][half * 64][0]);
      }
    }
  };

  const int nt = K / BK;
  stage(0, 0);
  if (DEPTH == 2 && nt > 1) stage(1, BK);
  int cur = 0, nxt = (DEPTH == 2) ? 2 : 1;
  for (int t = 0; t < nt; t++) {
    if constexpr (DEPTH == 1) {
      if (t + 1 < nt) {
        stage(nxt, (t + 1) * BK);
        wait_vm<CPW>();
      } else {
        wait_vm<0>();
      }
    } else {
      if (t + 2 < nt) {
        stage(nxt, (t + 2) * BK);
        wait_vm<2 * CPW>();
      } else if (t + 1 < nt) {
        wait_vm<CPW>();
      } else {
        wait_vm<0>();
      }
    }
    __builtin_amdgcn_s_barrier();
    __builtin_amdgcn_sched_barrier(0);

    const int fr = lane & 15, kc2 = lane >> 4;
#pragma unroll
    for (int kb = 0; kb < NKC / 4; kb++) {
      const int kcc = 4 * kb + kc2;
      f16x8 ah[MI], bh[4], alx[MI], blx[4];
#pragma unroll
      for (int i = 0; i < MI; i++) {
        ah[i] = *(const f16x8*)&smA[cur][0][kcc][wm * (TMI / 2) + i * 16 + fr][0];
        if (ALO) alx[i] = *(const f16x8*)&smA[cur][NMA - 1][kcc][wm * (TMI / 2) + i * 16 + fr][0];
      }
#pragma unroll
      for (int j = 0; j < 4; j++) {
        bh[j] = *(const f16x8*)&smB[cur][0][kcc][wn * 64 + j * 16 + fr][0];
        if (BLO) blx[j] = *(const f16x8*)&smB[cur][NMB - 1][kcc][wn * 64 + j * 16 + fr][0];
      }
#pragma unroll
      for (int i = 0; i < MI; i++)
#pragma unroll
        for (int j = 0; j < 4; j++) {
          acc[i][j] = __builtin_amdgcn_mfma_f32_16x16x32_f16(ah[i], bh[j], acc[i][j], 0, 0, 0);
          if (BLO) acc[i][j] = __builtin_amdgcn_mfma_f32_16x16x32_f16(ah[i], blx[j], acc[i][j], 0, 0, 0);
          if (ALO) acc[i][j] = __builtin_amdgcn_mfma_f32_16x16x32_f16(alx[i], bh[j], acc[i][j], 0, 0, 0);
        }
    }
    __builtin_amdgcn_sched_barrier(0);
    __builtin_amdgcn_s_barrier();
    cur = (cur == NBUF - 1) ? 0 : cur + 1;
    nxt = (nxt == NBUF - 1) ? 0 : nxt + 1;
  }

  const int fr0 = lane & 15, rg = lane >> 4;
  const int colb = bn + wn * 64 + fr0;
  const int rowb = bm + wm * (TMI / 2) + rg * 4;
  const long Co = (long)za * sCa + (long)zb * sCb;
#pragma unroll
  for (int i = 0; i < MI; i++)
#pragma unroll
    for (int j = 0; j < 4; j++)
#pragma unroll
      for (int r = 0; r < 4; r++) {
        int row = rowb + i * 16 + r;
        int col = colb + j * 16;
        float v = acc[i][j][r] * desc;
        long idx = Co + (long)row * ldc + col;
        if constexpr (EPI == E_PP) {
          unsigned short h = f16h(v);
          ((unsigned short*)C)[idx] = h;
          ((unsigned short*)C2)[idx] = f16h(v - f16tof(h));
        } else if constexpr (EPI == E_QKV) {
          int t2 = row & (TS - 1);
          v *= filtp[t2];
          if (t2 == 0) v = fmaf(1024.f * filtp[0], bias[col], v);
          int seg = col >> 10, nn = col & 1023;
          long oix = (long)row * 1024 + nn;
          if (seg == 0) {
            unsigned short h = f16h(v);
            ((unsigned short*)C)[oix] = h;
            ((unsigned short*)C2)[oix] = f16h(v - f16tof(h));
          } else {
            unsigned short h = f16h(v);
            ((unsigned short*)C3)[oix] = h;
            ((unsigned short*)C4)[oix] = f16h(v - f16tof(h));
          }
        } else if constexpr (EPI == E_V) {
          int t2 = row & (TS - 1);
          v *= filtp[t2];
          if (t2 == 0) v = fmaf(1024.f * filtp[0], bias[col], v);
          ((unsigned short*)C)[idx] = f16h(v);
        } else if constexpr (EPI == E_P16) {
          ((unsigned short*)C)[idx] = f16h(v);
        } else if constexpr (EPI == E_F32) {
          ((float*)C)[idx] = v;
        } else if constexpr (EPI == E_F32_BIAS) {
          ((float*)C)[idx] = v + bias[col];
        } else if constexpr (EPI == E_P1_GELU) {
          v += bias[col];
          v = 0.5f * v * (1.f + erff(v * 0.7071067811865476f));
          ((unsigned short*)C)[idx] = f16h(v);
        } else if constexpr (EPI == E_F32_ACC_BIAS) {
          ((float*)C)[idx] += v + bias[col];
        } else {  // E_F32_ATOMIC
          if (za == 0) v += bias[col];
          atomicAdd(&((float*)C)[(long)row * ldc + col], v);
        }
      }
}

// ---------------- softmax -> f16 plane ----------------
__global__ __launch_bounds__(256) void softmax_p(const float* __restrict__ S,
                                                 unsigned short* __restrict__ P,
                                                 float scale) {
  __shared__ float red[4];
  int row = blockIdx.x, tid = threadIdx.x;
  float4 v = ((const float4*)(S + (size_t)row * 1024))[tid];
  v.x *= scale; v.y *= scale; v.z *= scale; v.w *= scale;
  float m = fmaxf(fmaxf(v.x, v.y), fmaxf(v.z, v.w));
  m = blockMax(m, red, 4);
  float4 e;
  e.x = expf(v.x - m); e.y = expf(v.y - m); e.z = expf(v.z - m); e.w = expf(v.w - m);
  float s = e.x + e.y + e.z + e.w;
  s = blockSum(s, red, 4);
  float inv = 1.f / s;
  u16x4 o;
  o[0] = f16h(e.x * inv); o[1] = f16h(e.y * inv);
  o[2] = f16h(e.z * inv); o[3] = f16h(e.w * inv);
  *(u16x4*)(P + (size_t)row * 1024 + tid * 4) = o;
}

// ---------------- two-stage mean-pool + classifier ----------------
__global__ __launch_bounds__(256) void pool_partial(const float* __restrict__ x,
                                                    float* __restrict__ part) {
  int b = blockIdx.x, c = blockIdx.y, tid = threadIdx.x;
  const float* xb = x + ((size_t)b * TS + c * 64) * DM;
  float4 s = {0.f, 0.f, 0.f, 0.f};
  for (int r = 0; r < 64; r++) {
    float4 v = ((const float4*)(xb + (size_t)r * DM))[tid];
    s.x += v.x; s.y += v.y; s.z += v.z; s.w += v.w;
  }
  ((float4*)(part + (size_t)(b * 16 + c) * DM))[tid] = s;
}
__global__ __launch_bounds__(1024) void pool_cls2(const float* __restrict__ part,
                                                  const float* __restrict__ clsW,
                                                  const float* __restrict__ clsb,
                                                  float* __restrict__ out) {
  __shared__ float red[16];
  int b = blockIdx.x, d = threadIdx.x;
  float s = 0.f;
  for (int c = 0; c < 16; c++) s += part[(size_t)(b * 16 + c) * DM + d];
  float p = s * (1.f / 1024.f);
  float a0 = p * clsW[d * 2 + 0];
  float a1 = p * clsW[d * 2 + 1];
  a0 = blockSum(a0, red, 16);
  a1 = blockSum(a1, red, 16);
  if (d == 0) {
    out[b * 2 + 0] = a0 + clsb[0];
    out[b * 2 + 1] = a1 + clsb[1];
  }
}

// ---------------- driver ----------------
extern "C" void kernel_launch(void* const* d_in, const int* in_sizes, int n_in,
                              void* d_out, int out_size, void* d_ws, size_t ws_size,
                              hipStream_t stream) {
  (void)in_sizes; (void)n_in; (void)out_size; (void)ws_size;
  const int*   ids        = (const int*)  d_in[0];
  const float* tok_table  = (const float*)d_in[1];
  const float* emb_scales = (const float*)d_in[2];
  const float* emb_norm   = (const float*)d_in[3];
  const float* pos_emb    = (const float*)d_in[4];
  const float* W_el       = (const float*)d_in[5];
  const float* b_el       = (const float*)d_in[6];
  const float* W_le       = (const float*)d_in[7];
  const float* b_le       = (const float*)d_in[8];
  const float* ecs        = (const float*)d_in[9];
  const float* epres      = (const float*)d_in[10];
  const float* ln1_w      = (const float*)d_in[11];
  const float* ln1_b      = (const float*)d_in[12];
  const float* ln2_w      = (const float*)d_in[13];
  const float* ln2_b      = (const float*)d_in[14];
  const float* qW = (const float*)d_in[15]; const float* qb = (const float*)d_in[16];
  const float* kW = (const float*)d_in[17]; const float* kb = (const float*)d_in[18];
  const float* vW = (const float*)d_in[19]; const float* vb = (const float*)d_in[20];
  const float* oW = (const float*)d_in[21]; const float* ob = (const float*)d_in[22];
  const float* f1W = (const float*)d_in[23]; const float* f1b = (const float*)d_in[24];
  const float* f2W = (const float*)d_in[25]; const float* f2b = (const float*)d_in[26];
  const float* alpha  = (const float*)d_in[27];
  const float* fscale = (const float*)d_in[28];
  const float* enorm  = (const float*)d_in[29];
  const float* clsW   = (const float*)d_in[30];
  const float* clsb   = (const float*)d_in[31];

  const size_t MB = 1u << 20;
  const long M1 = 1048576;
  char* p = (char*)d_ws;
  auto take = [&](size_t n) { char* r = p; p += n; return r; };
  unsigned short* CtH = (unsigned short*)take(2 * MB);
  unsigned short* CtL = (unsigned short*)take(2 * MB);
  float* filt    = (float*)take(16 * 1024);
  float* hnorm   = (float*)take(16 * 1024);
  float* bias3   = (float*)take(64 * 1024);   // [3][3072]
  float* W_elT   = (float*)take(128 * 1024);
  float* part    = (float*)take(1 * MB);
  float* x       = (float*)take(16 * MB);
  unsigned short* BIG = (unsigned short*)take(64 * MB);
  unsigned short* Hh  = BIG,            *Hl  = BIG + 4 * M1;
  unsigned short* HTh = BIG + 8 * M1,   *HTl = BIG + 12 * M1;
  unsigned short* HCh = BIG + 16 * M1,  *HCl = BIG + 20 * M1;
  unsigned short* WTh = BIG + 24 * M1,  *WTl = BIG + 28 * M1;
  unsigned short* P   = BIG;
  unsigned short* QFh = (unsigned short*)take(8 * MB);
  unsigned short* QFl = (unsigned short*)take(8 * MB);
  unsigned short* KFh = (unsigned short*)take(8 * MB);
  unsigned short* KFl = (unsigned short*)take(8 * MB);
  unsigned short* VT  = (unsigned short*)take(8 * MB);
  float* SREG = (float*)take(32 * MB);
  unsigned short* atth = (unsigned short*)SREG;
  float* OUTP = SREG + 4 * M1;
  unsigned short* MID = (unsigned short*)SREG;
  unsigned short* Vtmp = HTh;

  const float WS = 1024.f;
  const float DS = 1.f / 1024.f;
  const float scale = 0.08838834764831845f;

  build_C_pp<<<4096, 256, 0, stream>>>(CtH, CtL);
  build_filt<<<1, 1024, 0, stream>>>(filt, alpha, fscale);
  trans_wel<<<96, 256, 0, stream>>>(W_el, W_elT);
  biascat3_all<<<36, 256, 0, stream>>>(qb, kb, vb, bias3);
  embed_kernel<<<NROWS, 256, 0, stream>>>(ids, tok_table, emb_scales, emb_norm, pos_emb, x);
  leech_wave<<<1024, 256, 0, stream>>>(x, W_elT, b_el, W_le, b_le, ecs, epres);

  dim3 t44(16, 16, 4), t11(16, 16, 1);
  for (int i = 0; i < LL; i++) {
    ln_pp<<<NROWS, 256, 0, stream>>>(x, ln1_w + i * DM, ln1_b + i * DM, Hh, Hl, hnorm);
    tsplit_u16<<<dim3(16, 16, 8), 256, 0, stream>>>(Hh, HTh, 1024, 1024, M1, M1);
    gemmT<E_PP, true, true, 64, 2><<<dim3(8, 16, 4), 256, 0, stream>>>(
        CtH, CtL, HTh, HTl, HCh, HCl, nullptr, nullptr, nullptr,
        nullptr, nullptr, 1.f, 1024, 1024, 1024, 1024, 1, 0, 0, M1, 0, M1, 0);
    tsplit_f32<<<t11, 256, 0, stream>>>(qW + (size_t)i * M1, WTh, WTl, 1024, 1024, WS);
    tsplit_f32<<<t11, 256, 0, stream>>>(kW + (size_t)i * M1, WTh + M1, WTl + M1, 1024, 1024, WS);
    tsplit_f32<<<t11, 256, 0, stream>>>(vW + (size_t)i * M1, WTh + 2 * M1, nullptr, 1024, 1024, WS);
    gemmT<E_QKV, true, true, 128, 1><<<dim3(16, 32, 1), 256, 0, stream>>>(
        HCh, HCl, WTh, WTl, QFh, QFl, KFh, KFl, nullptr,
        bias3 + i * 3072, filt + i * TS, DS, 1024, 1024, 1024, 1024, 1, 0, 0, 0, 0, 0, 0);
    gemmT<E_V, false, false, 64, 2><<<dim3(8, 64, 1), 256, 0, stream>>>(
        HCh, nullptr, WTh + 2 * M1, nullptr, Vtmp, nullptr, nullptr, nullptr, nullptr,
        vb + i * DM, filt + i * TS, DS, 1024, 1024, 1024, 1024, 1, 0, 0, 0, 0, 0, 0);
    tsplit_u16<<<t44, 256, 0, stream>>>(Vtmp, VT, 1024, 1024, M1, M1);
    // attention: QKT per b at TMI=128; softmax; batched PV (f16-only out)
    for (int b = 0; b < BB; b++) {
      gemmT<E_F32, true, true, 128, 1><<<dim3(8, 8, 8), 256, 0, stream>>>(
          QFh + (size_t)b * M1, QFl + (size_t)b * M1,
          KFh + (size_t)b * M1, KFl + (size_t)b * M1,
          SREG, nullptr, nullptr, nullptr, nullptr,
          nullptr, nullptr, 1.f, 128, 1024, 1024, 1024, 1, 128, 0, 128, 0, M1, 0);
      softmax_p<<<HH * TS, 256, 0, stream>>>(SREG, P + (size_t)b * 8 * M1, scale);
    }
    gemmT<E_P16, false, false, 64, 2><<<dim3(1, 16, 32), 256, 0, stream>>>(
        P, nullptr, VT, nullptr, atth, nullptr, nullptr, nullptr, nullptr,
        nullptr, nullptr, 1.f, 1024, 1024, 1024, 1024, 8,
        8L * M1, M1, M1, 131072, M1, 128);
    // o-proj: 1-term, TMI=64, DEPTH=2, direct f32+bias store
    tsplit_f32<<<t11, 256, 0, stream>>>(oW + (size_t)i * M1, WTh, nullptr, 1024, 1024, WS);
    gemmT<E_F32_BIAS, false, false, 64, 2><<<dim3(8, 64, 1), 256, 0, stream>>>(
        atth, nullptr, WTh, nullptr, OUTP, nullptr, nullptr, nullptr, nullptr,
        ob + i * DM, nullptr, DS, 1024, 1024, 1024, 1024, 1, 0, 0, 0, 0, 0, 0);
    // fused residual-scale + LN2 -> Hh (saves x re-read + one launch)
    outscale_ln<<<NROWS, 256, 0, stream>>>(x, OUTP, hnorm, enorm + i,
                                           ln2_w + i * DM, ln2_b + i * DM, Hh);
    // FFN (round-14 optimum configs)
    tsplit_f32<<<dim3(64, 16, 1), 256, 0, stream>>>(f1W + (size_t)i * 4 * M1, WTh, nullptr, 4096, 1024, WS);
    gemmT<E_P1_GELU, false, false, 128, 1, 8><<<dim3(32, 32, 1), 256, 0, stream>>>(
        Hh, nullptr, WTh, nullptr, MID, nullptr, nullptr, nullptr, nullptr,
        f1b + i * DFF, nullptr, DS, 1024, 1024, 1024, 4096, 1, 0, 0, 0, 0, 0, 0);
    tsplit_f32<<<dim3(16, 64, 1), 256, 0, stream>>>(f2W + (size_t)i * 4 * M1, WTh, nullptr, 1024, 4096, WS);
    gemmT<E_F32_ATOMIC, false, false, 128, 1, 8><<<dim3(8, 32, 2), 256, 0, stream>>>(
        MID, nullptr, WTh, nullptr, x, nullptr, nullptr, nullptr, nullptr,
        f2b + i * DM, nullptr, DS, 2048, 4096, 4096, 1024, 1, 2048, 0, 2048, 0, 0, 0);
  }
  pool_partial<<<dim3(BB, 16), 256, 0, stream>>>(x, part);
  pool_cls2<<<BB, 1024, 0, stream>>>(part, clsW, clsb, (float*)d_out);
}